// Round 2
// baseline (2467.026 us; speedup 1.0000x reference)
//
#include <hip/hip_runtime.h>
#include <hip/hip_bf16.h>
#include <cstdint>

// Problem constants (fixed by the reference)
#define NN 30000
#define EE 480000
#define GG 64

// ---------------------------------------------------------------- CSR build
__global__ void count_deg_k(const int* __restrict__ ei, int* __restrict__ deg) {
    int e = blockIdx.x * 256 + threadIdx.x;
    if (e < EE) atomicAdd(&deg[ei[EE + e]], 1);
}

// single-block exclusive scan over n entries
__global__ void scan_excl_k(const int* __restrict__ deg, int* __restrict__ basep, int n) {
    __shared__ int buf[1024];
    int tid = threadIdx.x;
    int carry = 0;
    for (int start = 0; start < n; start += 1024) {
        int i = start + tid;
        int v = (i < n) ? deg[i] : 0;
        __syncthreads();
        buf[tid] = v;
        __syncthreads();
        for (int off = 1; off < 1024; off <<= 1) {
            int t = (tid >= off) ? buf[tid - off] : 0;
            __syncthreads();
            buf[tid] += t;
            __syncthreads();
        }
        if (i < n) basep[i] = carry + buf[tid] - v;
        carry += buf[1023];
    }
    if (tid == 0) basep[n] = carry;
}

__global__ void fill_csr_k(const int* __restrict__ ei, const float* __restrict__ ea,
                           const int* __restrict__ basep, int* __restrict__ cnt,
                           int* __restrict__ csrc, float* __restrict__ cea) {
    int e = blockIdx.x * 256 + threadIdx.x;
    if (e < EE) {
        int d = ei[EE + e];
        int pos = basep[d] + atomicAdd(&cnt[d], 1);
        csrc[pos] = ei[e];
        cea[pos] = ea[e];
    }
}

// ---------------------------------------------------------------- fp32 GEMM
// C[M,N] = A[M,K] @ W[K,N] + bias[N].  BM=BN=64, BK=16, 256 thr, 4x4/thread.
__global__ __launch_bounds__(256) void gemm_bias_k(
    const float* __restrict__ A, const float* __restrict__ W,
    const float* __restrict__ bias, float* __restrict__ C,
    int M, int K, int N) {
    __shared__ float As[16][65];
    __shared__ float Bs[16][65];
    int t = threadIdx.x;
    int tx = t & 15, ty = t >> 4;
    int m0 = blockIdx.y * 64, n0 = blockIdx.x * 64;
    float c[4][4] = {};
    for (int k0 = 0; k0 < K; k0 += 16) {
        int ar = t >> 2, ac = (t & 3) * 4;
        float4 av = make_float4(0.f, 0.f, 0.f, 0.f);
        if (m0 + ar < M)
            av = *reinterpret_cast<const float4*>(&A[(size_t)(m0 + ar) * K + k0 + ac]);
        As[ac + 0][ar] = av.x; As[ac + 1][ar] = av.y;
        As[ac + 2][ar] = av.z; As[ac + 3][ar] = av.w;
        int wr = t >> 4, wc = (t & 15) * 4;
        float4 wv = *reinterpret_cast<const float4*>(&W[(size_t)(k0 + wr) * N + n0 + wc]);
        Bs[wr][wc + 0] = wv.x; Bs[wr][wc + 1] = wv.y;
        Bs[wr][wc + 2] = wv.z; Bs[wr][wc + 3] = wv.w;
        __syncthreads();
#pragma unroll
        for (int k = 0; k < 16; ++k) {
            float a0[4], b0[4];
#pragma unroll
            for (int i = 0; i < 4; i++) { a0[i] = As[k][ty * 4 + i]; b0[i] = Bs[k][tx * 4 + i]; }
#pragma unroll
            for (int i = 0; i < 4; i++)
#pragma unroll
                for (int j = 0; j < 4; j++) c[i][j] += a0[i] * b0[j];
        }
        __syncthreads();
    }
#pragma unroll
    for (int i = 0; i < 4; i++) {
        int row = m0 + ty * 4 + i;
        if (row < M) {
#pragma unroll
            for (int j = 0; j < 4; j++) {
                int col = n0 + tx * 4 + j;
                C[(size_t)row * N + col] = c[i][j] + bias[col];
            }
        }
    }
}

// ---------------------------------------------------------------- aggregate
template <int VEC>
__device__ inline void loadvec(const float* __restrict__ p, float (&r)[VEC]) {
    if constexpr (VEC == 2) {
        float2 t = *reinterpret_cast<const float2*>(p);
        r[0] = t.x; r[1] = t.y;
    } else {
#pragma unroll
        for (int i = 0; i < VEC; i += 4) {
            float4 t = *reinterpret_cast<const float4*>(p + i);
            r[i] = t.x; r[i + 1] = t.y; r[i + 2] = t.z; r[i + 3] = t.w;
        }
    }
}

// One wave per destination node. Lanes: head g spans L = 64/H lanes.
// S (skip, bias already added) lives in `out` — read own row, then overwrite.
template <int H, int D, bool RELU>
__global__ __launch_bounds__(256) void aggregate_k(
    const float* __restrict__ Q, const float* __restrict__ K,
    const float* __restrict__ V,
    const float* __restrict__ ew,
    const int* __restrict__ rowptr, const int* __restrict__ csrc,
    const float* __restrict__ cea, float* __restrict__ out) {
    constexpr int F = H * D;
    constexpr int VEC = F / 64;
    constexpr int L = 64 / H;        // lanes per head
    int lane = threadIdx.x & 63;
    int wid = threadIdx.x >> 6;
    int node = blockIdx.x * 4 + wid;
    if (node >= NN) return;

    float q[VEC], ewv[VEC], acc[VEC], sv[VEC];
    loadvec<VEC>(Q + (size_t)node * F + lane * VEC, q);
    loadvec<VEC>(ew + lane * VEC, ewv);
    loadvec<VEC>(out + (size_t)node * F + lane * VEC, sv);   // skip row
#pragma unroll
    for (int i = 0; i < VEC; i++) acc[i] = 0.f;

    float m = -INFINITY, den = 0.f;
    const float isd = rsqrtf((float)D);
    int beg = rowptr[node], end = rowptr[node + 1];
    for (int idx = beg; idx < end; ++idx) {
        int src = csrc[idx];
        float eav = cea[idx];
        float kv[VEC], vv[VEC];
        loadvec<VEC>(K + (size_t)src * F + lane * VEC, kv);
        loadvec<VEC>(V + (size_t)src * F + lane * VEC, vv);
        float p = 0.f;
#pragma unroll
        for (int i = 0; i < VEC; i++) p += q[i] * (kv[i] + eav * ewv[i]);
#pragma unroll
        for (int off = 1; off < L; off <<= 1) p += __shfl_xor(p, off, 64);
        float s = p * isd;
        float mnew = fmaxf(m, s);
        float scale = __expf(m - mnew);
        float w = __expf(s - mnew);
        den = den * scale + w;
#pragma unroll
        for (int i = 0; i < VEC; i++) acc[i] = acc[i] * scale + w * (vv[i] + eav * ewv[i]);
        m = mnew;
    }
    float rden = (den > 0.f) ? 1.f / den : 0.f;
    float* orow = out + (size_t)node * F + lane * VEC;
#pragma unroll
    for (int i = 0; i < VEC; i++) {
        float o = acc[i] * rden + sv[i];
        if (RELU) o = fmaxf(o, 0.f);
        orow[i] = o;
    }
}

// ---------------------------------------------------------------- pool+head
__global__ void pool_sum_k(const float* __restrict__ h3, const int* __restrict__ batch,
                           float* __restrict__ pooled, float* __restrict__ gcnt) {
    int idx = blockIdx.x * 256 + threadIdx.x;
    if (idx < NN * 128) {
        int node = idx >> 7, d = idx & 127;
        int g = batch[node];
        atomicAdd(&pooled[g * 128 + d], h3[idx]);
        if (d == 0) atomicAdd(&gcnt[g], 1.0f);
    }
}

__global__ void head_k(const float* __restrict__ pooled, const float* __restrict__ gcnt,
                       const float* __restrict__ lw, const float* __restrict__ lb,
                       float* __restrict__ out) {
    int g = blockIdx.x, o = threadIdx.x;
    if (o < 13) {
        float cnt = fmaxf(gcnt[g], 1.0f);
        float s = 0.f;
        for (int d = 0; d < 128; ++d) s += pooled[g * 128 + d] * lw[d * 13 + o];
        out[g * 13 + o] = s / cnt + lb[o];
    }
}

// diagnostic: ws too small -> fill output with a distinctive value
__global__ void ws_fail_k(float* __restrict__ out, int n) {
    int i = blockIdx.x * 256 + threadIdx.x;
    if (i < n) out[i] = -12345.0f;
}

// ---------------------------------------------------------------- launch
extern "C" void kernel_launch(void* const* d_in, const int* in_sizes, int n_in,
                              void* d_out, int out_size, void* d_ws, size_t ws_size,
                              hipStream_t stream) {
    const float* x   = (const float*)d_in[0];
    const int*   ei  = (const int*)d_in[1];
    const float* ea  = (const float*)d_in[2];
    const int*   bat = (const int*)d_in[3];
    const float* q1w = (const float*)d_in[4];  const float* q1b = (const float*)d_in[5];
    const float* k1w = (const float*)d_in[6];  const float* k1b = (const float*)d_in[7];
    const float* v1w = (const float*)d_in[8];  const float* v1b = (const float*)d_in[9];
    const float* e1w = (const float*)d_in[10];
    const float* s1w = (const float*)d_in[11]; const float* s1b = (const float*)d_in[12];
    const float* q2w = (const float*)d_in[13]; const float* q2b = (const float*)d_in[14];
    const float* k2w = (const float*)d_in[15]; const float* k2b = (const float*)d_in[16];
    const float* v2w = (const float*)d_in[17]; const float* v2b = (const float*)d_in[18];
    const float* e2w = (const float*)d_in[19];
    const float* s2w = (const float*)d_in[20]; const float* s2b = (const float*)d_in[21];
    const float* q3w = (const float*)d_in[22]; const float* q3b = (const float*)d_in[23];
    const float* k3w = (const float*)d_in[24]; const float* k3b = (const float*)d_in[25];
    const float* v3w = (const float*)d_in[26]; const float* v3b = (const float*)d_in[27];
    const float* e3w = (const float*)d_in[28];
    const float* s3w = (const float*)d_in[29]; const float* s3b = (const float*)d_in[30];
    const float* lw  = (const float*)d_in[31]; const float* lb  = (const float*)d_in[32];

    char* wsb = (char*)d_ws;
    size_t off = 0;
    auto alloc_f = [&](size_t elems) {
        void* p = wsb + off;
        off += ((elems * 4 + 255) / 256) * 256;
        return (float*)p;
    };
    // 4 big fp32 buffers (NN x 512 each), reused across layers
    float* bufQ = alloc_f((size_t)NN * 512);
    float* bufK = alloc_f((size_t)NN * 512);
    float* bufV = alloc_f((size_t)NN * 512);
    float* bufH = alloc_f((size_t)NN * 512);
    int*   basep = (int*)alloc_f(NN + 1);
    int*   csrc  = (int*)alloc_f(EE);
    float* cea   = alloc_f(EE);
    size_t zstart = off;
    int*   deg    = (int*)alloc_f(NN);
    int*   cnt    = (int*)alloc_f(NN);
    float* pooled = alloc_f(GG * 128);
    float* gcnt   = alloc_f(GG);
    size_t zbytes = off - zstart;

    if (ws_size < off) {  // workspace too small: fail loudly but without faulting
        ws_fail_k<<<(out_size + 255) / 256, 256, 0, stream>>>((float*)d_out, out_size);
        return;
    }

    hipMemsetAsync(wsb + zstart, 0, zbytes, stream);

    int eblocks = (EE + 255) / 256;
    count_deg_k<<<eblocks, 256, 0, stream>>>(ei, deg);
    scan_excl_k<<<1, 1024, 0, stream>>>(deg, basep, NN);
    fill_csr_k<<<eblocks, 256, 0, stream>>>(ei, ea, basep, cnt, csrc, cea);

    dim3 blk(256);
    // ---- layer 1: in 256 -> H=8,D=64 (F=512). Q=bufQ K=bufK V=bufV H1=bufH
    {
        dim3 grid(512 / 64, (NN + 63) / 64);
        gemm_bias_k<<<grid, blk, 0, stream>>>(x, q1w, q1b, bufQ, NN, 256, 512);
        gemm_bias_k<<<grid, blk, 0, stream>>>(x, k1w, k1b, bufK, NN, 256, 512);
        gemm_bias_k<<<grid, blk, 0, stream>>>(x, v1w, v1b, bufV, NN, 256, 512);
        gemm_bias_k<<<grid, blk, 0, stream>>>(x, s1w, s1b, bufH, NN, 256, 512);  // skip -> H1
        aggregate_k<8, 64, true><<<NN / 4, 256, 0, stream>>>(bufQ, bufK, bufV, e1w, basep, csrc, cea, bufH);
    }
    // ---- layer 2: in 512 (H1=bufH) -> H=4,D=64 (F=256).
    // Q2=bufQ[0:], H2=bufQ[NN*256:], K2=bufK, V2=bufV
    float* H2 = bufQ + (size_t)NN * 256;
    {
        dim3 grid(256 / 64, (NN + 63) / 64);
        gemm_bias_k<<<grid, blk, 0, stream>>>(bufH, q2w, q2b, bufQ, NN, 512, 256);
        gemm_bias_k<<<grid, blk, 0, stream>>>(bufH, k2w, k2b, bufK, NN, 512, 256);
        gemm_bias_k<<<grid, blk, 0, stream>>>(bufH, v2w, v2b, bufV, NN, 512, 256);
        gemm_bias_k<<<grid, blk, 0, stream>>>(bufH, s2w, s2b, H2,   NN, 512, 256);  // skip -> H2
        aggregate_k<4, 64, true><<<NN / 4, 256, 0, stream>>>(bufQ, bufK, bufV, e2w, basep, csrc, cea, H2);
    }
    // ---- layer 3: in 256 (H2) -> H=1,D=128 (F=128).
    // Q3=bufK[0:], K3=bufK[NN*128:], V3=bufV, H3=bufH
    float* Q3 = bufK;
    float* K3 = bufK + (size_t)NN * 128;
    float* H3 = bufH;
    {
        dim3 grid(128 / 64, (NN + 63) / 64);
        gemm_bias_k<<<grid, blk, 0, stream>>>(H2, q3w, q3b, Q3,   NN, 256, 128);
        gemm_bias_k<<<grid, blk, 0, stream>>>(H2, k3w, k3b, K3,   NN, 256, 128);
        gemm_bias_k<<<grid, blk, 0, stream>>>(H2, v3w, v3b, bufV, NN, 256, 128);
        gemm_bias_k<<<grid, blk, 0, stream>>>(H2, s3w, s3b, H3,   NN, 256, 128);  // skip -> H3
        aggregate_k<1, 128, false><<<NN / 4, 256, 0, stream>>>(Q3, K3, bufV, e3w, basep, csrc, cea, H3);
    }
    // ---- pool + head
    pool_sum_k<<<((size_t)NN * 128 + 255) / 256, 256, 0, stream>>>(H3, bat, pooled, gcnt);
    head_k<<<GG, 64, 0, stream>>>(pooled, gcnt, lw, lb, (float*)d_out);
}

// Round 3
// 1046.199 us; speedup vs baseline: 2.3581x; 2.3581x over previous
//
#include <hip/hip_runtime.h>
#include <hip/hip_bf16.h>
#include <cstdint>

#define NN 30000
#define EE 480000
#define GG 64

typedef __attribute__((ext_vector_type(8))) short bf16x8;
typedef __attribute__((ext_vector_type(4))) float float4v;
typedef __attribute__((ext_vector_type(4))) unsigned short ushort4v;

static __device__ inline unsigned short f2bf(float f) {
    unsigned u = __float_as_uint(f);
    unsigned r = (u + 0x7fff + ((u >> 16) & 1)) >> 16;   // RNE
    return (unsigned short)r;
}
static __device__ inline float bf2f(unsigned short u) {
    return __uint_as_float(((unsigned)u) << 16);
}

// ---------------------------------------------------------------- CSR build
__global__ void count_deg_k(const int* __restrict__ ei, int* __restrict__ deg) {
    int e = blockIdx.x * 256 + threadIdx.x;
    if (e < EE) atomicAdd(&deg[ei[EE + e]], 1);
}

__global__ void scan_excl_k(const int* __restrict__ deg, int* __restrict__ basep, int n) {
    __shared__ int buf[1024];
    int tid = threadIdx.x;
    int carry = 0;
    for (int start = 0; start < n; start += 1024) {
        int i = start + tid;
        int v = (i < n) ? deg[i] : 0;
        __syncthreads();
        buf[tid] = v;
        __syncthreads();
        for (int off = 1; off < 1024; off <<= 1) {
            int t = (tid >= off) ? buf[tid - off] : 0;
            __syncthreads();
            buf[tid] += t;
            __syncthreads();
        }
        if (i < n) basep[i] = carry + buf[tid] - v;
        carry += buf[1023];
    }
    if (tid == 0) basep[n] = carry;
}

__global__ void fill_csr_k(const int* __restrict__ ei, const float* __restrict__ ea,
                           const int* __restrict__ basep, int* __restrict__ cnt,
                           int* __restrict__ csrc, float* __restrict__ cea) {
    int e = blockIdx.x * 256 + threadIdx.x;
    if (e < EE) {
        int d = ei[EE + e];
        int pos = basep[d] + atomicAdd(&cnt[d], 1);
        csrc[pos] = ei[e];
        cea[pos] = ea[e];
    }
}

// ---------------------------------------------------------------- prep
// mode 0: flat f32 -> bf16 cast.  mode 1: transpose-cast W[K][N] -> Wt[N][K].
// mode 2: f32 copy (bias concat).
struct PrepDesc { const float* src; void* dst; int rows; int cols; int blk0; int mode; };
#define NDESC 25
struct PrepArgs { PrepDesc d[NDESC]; };

__global__ __launch_bounds__(256) void prep_k(PrepArgs args) {
    int b = blockIdx.x;
    PrepDesc dd = args.d[0];
#pragma unroll
    for (int i = 1; i < NDESC; i++)
        if (b >= args.d[i].blk0) dd = args.d[i];
    int rel = b - dd.blk0;
    int total = dd.rows * dd.cols;
    int base = rel * 1024 + threadIdx.x;
    if (dd.mode == 0) {
        unsigned short* dst = (unsigned short*)dd.dst;
        for (int j = 0; j < 4; j++) {
            int i = base + j * 256;
            if (i < total) dst[i] = f2bf(dd.src[i]);
        }
    } else if (dd.mode == 1) {
        unsigned short* dst = (unsigned short*)dd.dst;
        for (int j = 0; j < 4; j++) {
            int i = base + j * 256;
            if (i < total) {
                int n = i / dd.rows, k = i - n * dd.rows;
                dst[i] = f2bf(dd.src[(size_t)k * dd.cols + n]);
            }
        }
    } else {
        float* dst = (float*)dd.dst;
        for (int j = 0; j < 4; j++) {
            int i = base + j * 256;
            if (i < total) dst[i] = dd.src[i];
        }
    }
}

// ---------------------------------------------------------------- bf16 MFMA GEMM
// C[M][N] = A[M][K] @ Wt[N][K]^T + bias.  128x128 tile, BK=32, 256 thr (4 waves 2x2).
// LDS chunk-major [kc][row] (kc = k/8), staged via global_load_lds (16B/lane).
__global__ __launch_bounds__(256) void gemm_bf16_k(
    const unsigned short* __restrict__ A, const unsigned short* __restrict__ Wt,
    const float* __restrict__ bias, unsigned short* __restrict__ C,
    int M, int K, int N) {
    __shared__ unsigned short As[4096];   // 4 kc * 128 rows * 8 bf16 = 8KB
    __shared__ unsigned short Bs[4096];
    int tid = threadIdx.x;
    int lane = tid & 63, wid = tid >> 6;
    int wm = wid >> 1, wn = wid & 1;
    int row0 = blockIdx.y * 128, n0 = blockIdx.x * 128;

    float4v acc[4][4];
#pragma unroll
    for (int i = 0; i < 4; i++)
#pragma unroll
        for (int j = 0; j < 4; j++) acc[i][j] = (float4v)0.f;

    for (int k0 = 0; k0 < K; k0 += 32) {
#pragma unroll
        for (int i = 0; i < 2; ++i) {
            int chunkbase = i * 256 + wid * 64;          // wave-uniform
            int chunk = chunkbase + lane;
            int r = chunk & 127, kc = chunk >> 7;
            int rowA = row0 + r; if (rowA >= M) rowA = M - 1;
            const unsigned short* ga = A + (size_t)rowA * K + (k0 + kc * 8);
            __builtin_amdgcn_global_load_lds(
                (const __attribute__((address_space(1))) void*)ga,
                (__attribute__((address_space(3))) void*)(As + (size_t)chunkbase * 8),
                16, 0, 0);
            const unsigned short* gb = Wt + (size_t)(n0 + r) * K + (k0 + kc * 8);
            __builtin_amdgcn_global_load_lds(
                (const __attribute__((address_space(1))) void*)gb,
                (__attribute__((address_space(3))) void*)(Bs + (size_t)chunkbase * 8),
                16, 0, 0);
        }
        asm volatile("s_waitcnt vmcnt(0)" ::: "memory");
        __syncthreads();

        bf16x8 af[4], bfr[4];
#pragma unroll
        for (int mi = 0; mi < 4; mi++)
            af[mi] = *(const bf16x8*)(As + ((lane >> 4) * 128 + wm * 64 + mi * 16 + (lane & 15)) * 8);
#pragma unroll
        for (int ni = 0; ni < 4; ni++)
            bfr[ni] = *(const bf16x8*)(Bs + ((lane >> 4) * 128 + wn * 64 + ni * 16 + (lane & 15)) * 8);
#pragma unroll
        for (int mi = 0; mi < 4; mi++)
#pragma unroll
            for (int ni = 0; ni < 4; ni++)
                // swapped operands: lane holds (row = lane&15, 4 consecutive cols)
                acc[mi][ni] = __builtin_amdgcn_mfma_f32_16x16x32_bf16(
                    bfr[ni], af[mi], acc[mi][ni], 0, 0, 0);
        __syncthreads();
    }

    // epilogue: per frag, lane owns row = lane&15 (+mi*16), cols colb..colb+3
    float4v bias4[4];
#pragma unroll
    for (int ni = 0; ni < 4; ni++)
        bias4[ni] = *(const float4v*)&bias[n0 + wn * 64 + ni * 16 + (lane >> 4) * 4];
#pragma unroll
    for (int mi = 0; mi < 4; mi++) {
        int row = row0 + wm * 64 + mi * 16 + (lane & 15);
        if (row < M) {
#pragma unroll
            for (int ni = 0; ni < 4; ni++) {
                int colb = n0 + wn * 64 + ni * 16 + (lane >> 4) * 4;
                ushort4v pk;
#pragma unroll
                for (int r = 0; r < 4; r++) pk[r] = f2bf(acc[mi][ni][r] + bias4[ni][r]);
                *(ushort4v*)(C + (size_t)row * N + colb) = pk;
            }
        }
    }
}

// ---------------------------------------------------------------- aggregate
template <int VEC>
__device__ inline void loadbf(const unsigned short* __restrict__ p, float (&r)[VEC]) {
    if constexpr (VEC == 2) {
        unsigned v = *(const unsigned*)p;
        r[0] = __uint_as_float(v << 16);
        r[1] = __uint_as_float(v & 0xffff0000u);
    } else if constexpr (VEC == 4) {
        uint2 v = *(const uint2*)p;
        r[0] = __uint_as_float(v.x << 16); r[1] = __uint_as_float(v.x & 0xffff0000u);
        r[2] = __uint_as_float(v.y << 16); r[3] = __uint_as_float(v.y & 0xffff0000u);
    } else {
        uint4 v = *(const uint4*)p;
        r[0] = __uint_as_float(v.x << 16); r[1] = __uint_as_float(v.x & 0xffff0000u);
        r[2] = __uint_as_float(v.y << 16); r[3] = __uint_as_float(v.y & 0xffff0000u);
        r[4] = __uint_as_float(v.z << 16); r[5] = __uint_as_float(v.z & 0xffff0000u);
        r[6] = __uint_as_float(v.w << 16); r[7] = __uint_as_float(v.w & 0xffff0000u);
    }
}
template <int VEC>
__device__ inline void loadf32(const float* __restrict__ p, float (&r)[VEC]) {
    if constexpr (VEC == 2) {
        float2 t = *reinterpret_cast<const float2*>(p);
        r[0] = t.x; r[1] = t.y;
    } else {
#pragma unroll
        for (int i = 0; i < VEC; i += 4) {
            float4 t = *reinterpret_cast<const float4*>(p + i);
            r[i] = t.x; r[i + 1] = t.y; r[i + 2] = t.z; r[i + 3] = t.w;
        }
    }
}

// One wave per node. QKVS row: [Q | K | V | S], stride SR = 4F bf16.
template <int H, int D, bool RELU>
__global__ __launch_bounds__(256) void aggregate_k(
    const unsigned short* __restrict__ QKVS, int SR,
    const float* __restrict__ ew,
    const int* __restrict__ rowptr, const int* __restrict__ csrc,
    const float* __restrict__ cea, unsigned short* __restrict__ Hout) {
    constexpr int F = H * D;
    constexpr int VEC = F / 64;
    constexpr int L = 64 / H;
    int lane = threadIdx.x & 63;
    int wid = threadIdx.x >> 6;
    int node = blockIdx.x * 4 + wid;
    if (node >= NN) return;

    const unsigned short* qrow = QKVS + (size_t)node * SR;
    float q[VEC], ewv[VEC], acc[VEC], sv[VEC];
    loadbf<VEC>(qrow + lane * VEC, q);
    loadbf<VEC>(qrow + 3 * F + lane * VEC, sv);
    loadf32<VEC>(ew + lane * VEC, ewv);
#pragma unroll
    for (int i = 0; i < VEC; i++) acc[i] = 0.f;

    float m = -INFINITY, den = 0.f;
    const float isd = rsqrtf((float)D);
    int beg = rowptr[node], end = rowptr[node + 1];
    for (int idx = beg; idx < end; ++idx) {
        int src = csrc[idx];
        float eav = cea[idx];
        const unsigned short* kbase = QKVS + (size_t)src * SR + F;
        float kv[VEC], vv[VEC];
        loadbf<VEC>(kbase + lane * VEC, kv);
        loadbf<VEC>(kbase + F + lane * VEC, vv);
        float p = 0.f;
#pragma unroll
        for (int i = 0; i < VEC; i++) p += q[i] * (kv[i] + eav * ewv[i]);
#pragma unroll
        for (int off = 1; off < L; off <<= 1) p += __shfl_xor(p, off, 64);
        float s = p * isd;
        float mnew = fmaxf(m, s);
        float scale = __expf(m - mnew);
        float w = __expf(s - mnew);
        den = den * scale + w;
#pragma unroll
        for (int i = 0; i < VEC; i++) acc[i] = acc[i] * scale + w * (vv[i] + eav * ewv[i]);
        m = mnew;
    }
    float rden = (den > 0.f) ? 1.f / den : 0.f;
    unsigned short* orow = Hout + (size_t)node * F + lane * VEC;
#pragma unroll
    for (int i = 0; i < VEC; i++) {
        float o = acc[i] * rden + sv[i];
        if (RELU) o = fmaxf(o, 0.f);
        orow[i] = f2bf(o);
    }
}

// ---------------------------------------------------------------- pool+head
__global__ void pool_sum_k(const unsigned short* __restrict__ h3, const int* __restrict__ batch,
                           float* __restrict__ pooled, float* __restrict__ gcnt) {
    int idx = blockIdx.x * 256 + threadIdx.x;
    if (idx < NN * 128) {
        int node = idx >> 7, d = idx & 127;
        int g = batch[node];
        atomicAdd(&pooled[g * 128 + d], bf2f(h3[idx]));
        if (d == 0) atomicAdd(&gcnt[g], 1.0f);
    }
}

__global__ void head_k(const float* __restrict__ pooled, const float* __restrict__ gcnt,
                       const float* __restrict__ lw, const float* __restrict__ lb,
                       float* __restrict__ out) {
    int g = blockIdx.x, o = threadIdx.x;
    if (o < 13) {
        float cnt = fmaxf(gcnt[g], 1.0f);
        float s = 0.f;
        for (int d = 0; d < 128; ++d) s += pooled[g * 128 + d] * lw[d * 13 + o];
        out[g * 13 + o] = s / cnt + lb[o];
    }
}

__global__ void ws_fail_k(float* __restrict__ out, int n) {
    int i = blockIdx.x * 256 + threadIdx.x;
    if (i < n) out[i] = -12345.0f;
}

// ---------------------------------------------------------------- launch
extern "C" void kernel_launch(void* const* d_in, const int* in_sizes, int n_in,
                              void* d_out, int out_size, void* d_ws, size_t ws_size,
                              hipStream_t stream) {
    const float* x   = (const float*)d_in[0];
    const int*   ei  = (const int*)d_in[1];
    const float* ea  = (const float*)d_in[2];
    const int*   bat = (const int*)d_in[3];
    const float* W1[4] = {(const float*)d_in[4], (const float*)d_in[6], (const float*)d_in[8], (const float*)d_in[11]};
    const float* B1[4] = {(const float*)d_in[5], (const float*)d_in[7], (const float*)d_in[9], (const float*)d_in[12]};
    const float* e1w = (const float*)d_in[10];
    const float* W2[4] = {(const float*)d_in[13], (const float*)d_in[15], (const float*)d_in[17], (const float*)d_in[20]};
    const float* B2[4] = {(const float*)d_in[14], (const float*)d_in[16], (const float*)d_in[18], (const float*)d_in[21]};
    const float* e2w = (const float*)d_in[19];
    const float* W3[4] = {(const float*)d_in[22], (const float*)d_in[24], (const float*)d_in[26], (const float*)d_in[29]};
    const float* B3[4] = {(const float*)d_in[23], (const float*)d_in[25], (const float*)d_in[27], (const float*)d_in[30]};
    const float* e3w = (const float*)d_in[28];
    const float* lw  = (const float*)d_in[31];
    const float* lb  = (const float*)d_in[32];

    char* wsb = (char*)d_ws;
    size_t off = 0;
    auto alloc_b = [&](size_t bytes) {
        void* p = wsb + off;
        off += (bytes + 255) & ~(size_t)255;
        return p;
    };
    unsigned short* xb   = (unsigned short*)alloc_b((size_t)NN * 256 * 2);
    unsigned short* Wc1  = (unsigned short*)alloc_b((size_t)2048 * 256 * 2);
    float*          bc1  = (float*)alloc_b(2048 * 4);
    unsigned short* Wc2  = (unsigned short*)alloc_b((size_t)1024 * 512 * 2);
    float*          bc2  = (float*)alloc_b(1024 * 4);
    unsigned short* Wc3  = (unsigned short*)alloc_b((size_t)512 * 256 * 2);
    float*          bc3  = (float*)alloc_b(512 * 4);
    unsigned short* QKVS = (unsigned short*)alloc_b((size_t)NN * 2048 * 2);
    unsigned short* H1   = (unsigned short*)alloc_b((size_t)NN * 512 * 2);
    unsigned short* H2   = (unsigned short*)alloc_b((size_t)NN * 256 * 2);
    unsigned short* H3   = (unsigned short*)alloc_b((size_t)NN * 128 * 2);
    int*   basep = (int*)alloc_b((NN + 1) * 4);
    int*   csrc  = (int*)alloc_b((size_t)EE * 4);
    float* cea   = (float*)alloc_b((size_t)EE * 4);
    size_t zstart = off;
    int*   deg    = (int*)alloc_b(NN * 4);
    int*   cnt    = (int*)alloc_b(NN * 4);
    float* pooled = (float*)alloc_b(GG * 128 * 4);
    float* gcnt   = (float*)alloc_b(GG * 4);
    size_t zbytes = off - zstart;

    if (ws_size < off) {
        ws_fail_k<<<(out_size + 255) / 256, 256, 0, stream>>>((float*)d_out, out_size);
        return;
    }

    hipMemsetAsync(wsb + zstart, 0, zbytes, stream);

    // ---- prep descriptors
    PrepArgs pa;
    int blk = 0, di = 0;
    auto add = [&](const float* src, void* dst, int rows, int cols, int mode) {
        pa.d[di].src = src; pa.d[di].dst = dst;
        pa.d[di].rows = rows; pa.d[di].cols = cols;
        pa.d[di].mode = mode; pa.d[di].blk0 = blk;
        blk += (rows * cols + 1023) / 1024;
        di++;
    };
    add(x, xb, NN * 256, 1, 0);
    for (int s = 0; s < 4; s++) add(W1[s], Wc1 + (size_t)s * 512 * 256, 256, 512, 1);
    for (int s = 0; s < 4; s++) add(B1[s], bc1 + s * 512, 512, 1, 2);
    for (int s = 0; s < 4; s++) add(W2[s], Wc2 + (size_t)s * 256 * 512, 512, 256, 1);
    for (int s = 0; s < 4; s++) add(B2[s], bc2 + s * 256, 256, 1, 2);
    for (int s = 0; s < 4; s++) add(W3[s], Wc3 + (size_t)s * 128 * 256, 256, 128, 1);
    for (int s = 0; s < 4; s++) add(B3[s], bc3 + s * 128, 128, 1, 2);
    prep_k<<<blk, 256, 0, stream>>>(pa);

    int eblocks = (EE + 255) / 256;
    count_deg_k<<<eblocks, 256, 0, stream>>>(ei, deg);
    scan_excl_k<<<1, 1024, 0, stream>>>(deg, basep, NN);
    fill_csr_k<<<eblocks, 256, 0, stream>>>(ei, ea, basep, cnt, csrc, cea);

    int mblocks = (NN + 127) / 128;
    // ---- layer 1: x[30000,256] -> QKVS[30000,2048]
    gemm_bf16_k<<<dim3(2048 / 128, mblocks), 256, 0, stream>>>(xb, Wc1, bc1, QKVS, NN, 256, 2048);
    aggregate_k<8, 64, true><<<NN / 4, 256, 0, stream>>>(QKVS, 2048, e1w, basep, csrc, cea, H1);
    // ---- layer 2: H1[30000,512] -> QKVS[30000,1024]
    gemm_bf16_k<<<dim3(1024 / 128, mblocks), 256, 0, stream>>>(H1, Wc2, bc2, QKVS, NN, 512, 1024);
    aggregate_k<4, 64, true><<<NN / 4, 256, 0, stream>>>(QKVS, 1024, e2w, basep, csrc, cea, H2);
    // ---- layer 3: H2[30000,256] -> QKVS[30000,512]
    gemm_bf16_k<<<dim3(512 / 128, mblocks), 256, 0, stream>>>(H2, Wc3, bc3, QKVS, NN, 256, 512);
    aggregate_k<1, 128, false><<<NN / 4, 256, 0, stream>>>(QKVS, 512, e3w, basep, csrc, cea, H3);

    pool_sum_k<<<((size_t)NN * 128 + 255) / 256, 256, 0, stream>>>(H3, bat, pooled, gcnt);
    head_k<<<GG, 64, 0, stream>>>(pooled, gcnt, lw, lb, (float*)d_out);
}

// Round 4
// 854.617 us; speedup vs baseline: 2.8867x; 1.2242x over previous
//
#include <hip/hip_runtime.h>
#include <hip/hip_bf16.h>
#include <cstdint>

#define NN 30000
#define EE 480000
#define GG 64

typedef __attribute__((ext_vector_type(8))) short bf16x8;
typedef __attribute__((ext_vector_type(4))) float float4v;
typedef __attribute__((ext_vector_type(4))) unsigned short ushort4v;

static __device__ inline unsigned short f2bf(float f) {
    unsigned u = __float_as_uint(f);
    unsigned r = (u + 0x7fff + ((u >> 16) & 1)) >> 16;   // RNE
    return (unsigned short)r;
}
static __device__ inline float bf2f(unsigned short u) {
    return __uint_as_float(((unsigned)u) << 16);
}

// ---------------------------------------------------------------- CSR build
__global__ void count_deg_k(const int* __restrict__ ei, int* __restrict__ deg) {
    int e = blockIdx.x * 256 + threadIdx.x;
    if (e < EE) atomicAdd(&deg[ei[EE + e]], 1);
}

__global__ void scan_excl_k(const int* __restrict__ deg, int* __restrict__ basep, int n) {
    __shared__ int buf[1024];
    int tid = threadIdx.x;
    int carry = 0;
    for (int start = 0; start < n; start += 1024) {
        int i = start + tid;
        int v = (i < n) ? deg[i] : 0;
        __syncthreads();
        buf[tid] = v;
        __syncthreads();
        for (int off = 1; off < 1024; off <<= 1) {
            int t = (tid >= off) ? buf[tid - off] : 0;
            __syncthreads();
            buf[tid] += t;
            __syncthreads();
        }
        if (i < n) basep[i] = carry + buf[tid] - v;
        carry += buf[1023];
    }
    if (tid == 0) basep[n] = carry;
}

__global__ void fill_csr_k(const int* __restrict__ ei, const float* __restrict__ ea,
                           const int* __restrict__ basep, int* __restrict__ cnt,
                           int* __restrict__ csrc, float* __restrict__ cea) {
    int e = blockIdx.x * 256 + threadIdx.x;
    if (e < EE) {
        int d = ei[EE + e];
        int pos = basep[d] + atomicAdd(&cnt[d], 1);
        csrc[pos] = ei[e];
        cea[pos] = ea[e];
    }
}

// batch is sorted: find group start offsets (gstart[GG+1])
__global__ void gbound_k(const int* __restrict__ batch, int* __restrict__ gstart) {
    int i = blockIdx.x * 256 + threadIdx.x;
    if (i >= NN) return;
    int cur = batch[i];
    if (i == 0) {
        for (int g = 0; g <= cur; ++g) gstart[g] = 0;
    } else {
        int prev = batch[i - 1];
        for (int g = prev + 1; g <= cur; ++g) gstart[g] = i;
    }
    if (i == NN - 1) {
        for (int g = cur + 1; g <= GG; ++g) gstart[g] = NN;
    }
}

// ---------------------------------------------------------------- prep
// mode 0: flat f32 -> bf16 cast.  mode 1: transpose-cast W[K][N] -> Wt[N][K].
// mode 2: f32 copy (bias concat).
struct PrepDesc { const float* src; void* dst; int rows; int cols; int blk0; int mode; };
#define NDESC 25
struct PrepArgs { PrepDesc d[NDESC]; };

__global__ __launch_bounds__(256) void prep_k(PrepArgs args) {
    int b = blockIdx.x;
    PrepDesc dd = args.d[0];
#pragma unroll
    for (int i = 1; i < NDESC; i++)
        if (b >= args.d[i].blk0) dd = args.d[i];
    int rel = b - dd.blk0;
    int total = dd.rows * dd.cols;
    int base = rel * 1024 + threadIdx.x;
    if (dd.mode == 0) {
        unsigned short* dst = (unsigned short*)dd.dst;
        for (int j = 0; j < 4; j++) {
            int i = base + j * 256;
            if (i < total) dst[i] = f2bf(dd.src[i]);
        }
    } else if (dd.mode == 1) {
        unsigned short* dst = (unsigned short*)dd.dst;
        for (int j = 0; j < 4; j++) {
            int i = base + j * 256;
            if (i < total) {
                int n = i / dd.rows, k = i - n * dd.rows;
                dst[i] = f2bf(dd.src[(size_t)k * dd.cols + n]);
            }
        }
    } else {
        float* dst = (float*)dd.dst;
        for (int j = 0; j < 4; j++) {
            int i = base + j * 256;
            if (i < total) dst[i] = dd.src[i];
        }
    }
}

// ---------------------------------------------------------------- bf16 MFMA GEMM
// C[M][N] = A[M][K] @ Wt[N][K]^T + bias.  128x128 tile, BK=32, 256 thr (4 waves 2x2).
__global__ __launch_bounds__(256) void gemm_bf16_k(
    const unsigned short* __restrict__ A, const unsigned short* __restrict__ Wt,
    const float* __restrict__ bias, unsigned short* __restrict__ C,
    int M, int K, int N) {
    __shared__ unsigned short As[4096];   // 4 kc * 128 rows * 8 bf16 = 8KB
    __shared__ unsigned short Bs[4096];
    int tid = threadIdx.x;
    int lane = tid & 63, wid = tid >> 6;
    int wm = wid >> 1, wn = wid & 1;
    int row0 = blockIdx.y * 128, n0 = blockIdx.x * 128;

    float4v acc[4][4];
#pragma unroll
    for (int i = 0; i < 4; i++)
#pragma unroll
        for (int j = 0; j < 4; j++) acc[i][j] = (float4v)0.f;

    for (int k0 = 0; k0 < K; k0 += 32) {
#pragma unroll
        for (int i = 0; i < 2; ++i) {
            int chunkbase = i * 256 + wid * 64;          // wave-uniform
            int chunk = chunkbase + lane;
            int r = chunk & 127, kc = chunk >> 7;
            int rowA = row0 + r; if (rowA >= M) rowA = M - 1;
            const unsigned short* ga = A + (size_t)rowA * K + (k0 + kc * 8);
            __builtin_amdgcn_global_load_lds(
                (const __attribute__((address_space(1))) void*)ga,
                (__attribute__((address_space(3))) void*)(As + (size_t)chunkbase * 8),
                16, 0, 0);
            const unsigned short* gb = Wt + (size_t)(n0 + r) * K + (k0 + kc * 8);
            __builtin_amdgcn_global_load_lds(
                (const __attribute__((address_space(1))) void*)gb,
                (__attribute__((address_space(3))) void*)(Bs + (size_t)chunkbase * 8),
                16, 0, 0);
        }
        asm volatile("s_waitcnt vmcnt(0)" ::: "memory");
        __syncthreads();

        bf16x8 af[4], bfr[4];
#pragma unroll
        for (int mi = 0; mi < 4; mi++)
            af[mi] = *(const bf16x8*)(As + ((lane >> 4) * 128 + wm * 64 + mi * 16 + (lane & 15)) * 8);
#pragma unroll
        for (int ni = 0; ni < 4; ni++)
            bfr[ni] = *(const bf16x8*)(Bs + ((lane >> 4) * 128 + wn * 64 + ni * 16 + (lane & 15)) * 8);
#pragma unroll
        for (int mi = 0; mi < 4; mi++)
#pragma unroll
            for (int ni = 0; ni < 4; ni++)
                acc[mi][ni] = __builtin_amdgcn_mfma_f32_16x16x32_bf16(
                    bfr[ni], af[mi], acc[mi][ni], 0, 0, 0);
        __syncthreads();
    }

    float4v bias4[4];
#pragma unroll
    for (int ni = 0; ni < 4; ni++)
        bias4[ni] = *(const float4v*)&bias[n0 + wn * 64 + ni * 16 + (lane >> 4) * 4];
#pragma unroll
    for (int mi = 0; mi < 4; mi++) {
        int row = row0 + wm * 64 + mi * 16 + (lane & 15);
        if (row < M) {
#pragma unroll
            for (int ni = 0; ni < 4; ni++) {
                int colb = n0 + wn * 64 + ni * 16 + (lane >> 4) * 4;
                ushort4v pk;
#pragma unroll
                for (int r = 0; r < 4; r++) pk[r] = f2bf(acc[mi][ni][r] + bias4[ni][r]);
                *(ushort4v*)(C + (size_t)row * N + colb) = pk;
            }
        }
    }
}

// ---------------------------------------------------------------- aggregate
template <int VEC>
__device__ inline void loadbf(const unsigned short* __restrict__ p, float (&r)[VEC]) {
    if constexpr (VEC == 2) {
        unsigned v = *(const unsigned*)p;
        r[0] = __uint_as_float(v << 16);
        r[1] = __uint_as_float(v & 0xffff0000u);
    } else if constexpr (VEC == 4) {
        uint2 v = *(const uint2*)p;
        r[0] = __uint_as_float(v.x << 16); r[1] = __uint_as_float(v.x & 0xffff0000u);
        r[2] = __uint_as_float(v.y << 16); r[3] = __uint_as_float(v.y & 0xffff0000u);
    } else {
        uint4 v = *(const uint4*)p;
        r[0] = __uint_as_float(v.x << 16); r[1] = __uint_as_float(v.x & 0xffff0000u);
        r[2] = __uint_as_float(v.y << 16); r[3] = __uint_as_float(v.y & 0xffff0000u);
        r[4] = __uint_as_float(v.z << 16); r[5] = __uint_as_float(v.z & 0xffff0000u);
        r[6] = __uint_as_float(v.w << 16); r[7] = __uint_as_float(v.w & 0xffff0000u);
    }
}
template <int VEC>
__device__ inline void loadf32(const float* __restrict__ p, float (&r)[VEC]) {
    if constexpr (VEC == 2) {
        float2 t = *reinterpret_cast<const float2*>(p);
        r[0] = t.x; r[1] = t.y;
    } else {
#pragma unroll
        for (int i = 0; i < VEC; i += 4) {
            float4 t = *reinterpret_cast<const float4*>(p + i);
            r[i] = t.x; r[i + 1] = t.y; r[i + 2] = t.z; r[i + 3] = t.w;
        }
    }
}

// One wave per node. QKVS row: [Q | K | V | S], stride SR = 4F bf16.
// 1-deep software pipeline over the edge list to hide gather latency.
template <int H, int D, bool RELU>
__global__ __launch_bounds__(256) void aggregate_k(
    const unsigned short* __restrict__ QKVS, int SR,
    const float* __restrict__ ew,
    const int* __restrict__ rowptr, const int* __restrict__ csrc,
    const float* __restrict__ cea, unsigned short* __restrict__ Hout) {
    constexpr int F = H * D;
    constexpr int VEC = F / 64;
    constexpr int L = 64 / H;
    int lane = threadIdx.x & 63;
    int wid = threadIdx.x >> 6;
    int node = blockIdx.x * 4 + wid;
    if (node >= NN) return;

    const unsigned short* qrow = QKVS + (size_t)node * SR;
    float q[VEC], ewv[VEC], acc[VEC], sv[VEC];
    loadbf<VEC>(qrow + lane * VEC, q);
    loadbf<VEC>(qrow + 3 * F + lane * VEC, sv);
    loadf32<VEC>(ew + lane * VEC, ewv);
#pragma unroll
    for (int i = 0; i < VEC; i++) acc[i] = 0.f;

    float m = -INFINITY, den = 0.f;
    const float isd = rsqrtf((float)D);
    int beg = rowptr[node], end = rowptr[node + 1];

    float kv[VEC], vv[VEC], eav = 0.f;
    if (beg < end) {
        int src = csrc[beg];
        eav = cea[beg];
        const unsigned short* kb = QKVS + (size_t)src * SR + F;
        loadbf<VEC>(kb + lane * VEC, kv);
        loadbf<VEC>(kb + F + lane * VEC, vv);
    }
    for (int idx = beg; idx < end; ++idx) {
        float kn[VEC], vn[VEC], ean = 0.f;
        if (idx + 1 < end) {
            int srcn = csrc[idx + 1];
            ean = cea[idx + 1];
            const unsigned short* kb = QKVS + (size_t)srcn * SR + F;
            loadbf<VEC>(kb + lane * VEC, kn);
            loadbf<VEC>(kb + F + lane * VEC, vn);
        }
        float p = 0.f;
#pragma unroll
        for (int i = 0; i < VEC; i++) p += q[i] * (kv[i] + eav * ewv[i]);
#pragma unroll
        for (int off = 1; off < L; off <<= 1) p += __shfl_xor(p, off, 64);
        float s = p * isd;
        float mnew = fmaxf(m, s);
        float scale = __expf(m - mnew);
        float w = __expf(s - mnew);
        den = den * scale + w;
#pragma unroll
        for (int i = 0; i < VEC; i++) acc[i] = acc[i] * scale + w * (vv[i] + eav * ewv[i]);
        m = mnew;
        eav = ean;
#pragma unroll
        for (int i = 0; i < VEC; i++) { kv[i] = kn[i]; vv[i] = vn[i]; }
    }
    float rden = (den > 0.f) ? 1.f / den : 0.f;
    unsigned short* orow = Hout + (size_t)node * F + lane * VEC;
#pragma unroll
    for (int i = 0; i < VEC; i++) {
        float o = acc[i] * rden + sv[i];
        if (RELU) o = fmaxf(o, 0.f);
        orow[i] = f2bf(o);
    }
}

// ---------------------------------------------------------------- pool+head (fused, no atomics)
// One block per graph group; segmented mean over sorted batch, then 13-dim head.
__global__ __launch_bounds__(256) void pool_head_k(
    const unsigned short* __restrict__ h3, const int* __restrict__ gstart,
    const float* __restrict__ lw, const float* __restrict__ lb,
    float* __restrict__ out) {
    __shared__ float part[256];
    __shared__ float pooled[128];
    int g = blockIdx.x;
    int beg = gstart[g], end = gstart[g + 1];
    int d = threadIdx.x & 127, half = threadIdx.x >> 7;
    float s = 0.f;
    for (int node = beg + half; node < end; node += 2)
        s += bf2f(h3[(size_t)node * 128 + d]);
    part[threadIdx.x] = s;
    __syncthreads();
    if (threadIdx.x < 128) {
        float cnt = fmaxf((float)(end - beg), 1.0f);
        pooled[threadIdx.x] = (part[threadIdx.x] + part[threadIdx.x + 128]) / cnt;
    }
    __syncthreads();
    if (threadIdx.x < 13) {
        float acc = lb[threadIdx.x];
        for (int dd = 0; dd < 128; ++dd)
            acc += pooled[dd] * lw[dd * 13 + threadIdx.x];
        out[g * 13 + threadIdx.x] = acc;
    }
}

__global__ void ws_fail_k(float* __restrict__ out, int n) {
    int i = blockIdx.x * 256 + threadIdx.x;
    if (i < n) out[i] = -12345.0f;
}

// ---------------------------------------------------------------- launch
extern "C" void kernel_launch(void* const* d_in, const int* in_sizes, int n_in,
                              void* d_out, int out_size, void* d_ws, size_t ws_size,
                              hipStream_t stream) {
    const float* x   = (const float*)d_in[0];
    const int*   ei  = (const int*)d_in[1];
    const float* ea  = (const float*)d_in[2];
    const int*   bat = (const int*)d_in[3];
    const float* W1[4] = {(const float*)d_in[4], (const float*)d_in[6], (const float*)d_in[8], (const float*)d_in[11]};
    const float* B1[4] = {(const float*)d_in[5], (const float*)d_in[7], (const float*)d_in[9], (const float*)d_in[12]};
    const float* e1w = (const float*)d_in[10];
    const float* W2[4] = {(const float*)d_in[13], (const float*)d_in[15], (const float*)d_in[17], (const float*)d_in[20]};
    const float* B2[4] = {(const float*)d_in[14], (const float*)d_in[16], (const float*)d_in[18], (const float*)d_in[21]};
    const float* e2w = (const float*)d_in[19];
    const float* W3[4] = {(const float*)d_in[22], (const float*)d_in[24], (const float*)d_in[26], (const float*)d_in[29]};
    const float* B3[4] = {(const float*)d_in[23], (const float*)d_in[25], (const float*)d_in[27], (const float*)d_in[30]};
    const float* e3w = (const float*)d_in[28];
    const float* lw  = (const float*)d_in[31];
    const float* lb  = (const float*)d_in[32];

    char* wsb = (char*)d_ws;
    size_t off = 0;
    auto alloc_b = [&](size_t bytes) {
        void* p = wsb + off;
        off += (bytes + 255) & ~(size_t)255;
        return p;
    };
    unsigned short* xb   = (unsigned short*)alloc_b((size_t)NN * 256 * 2);
    unsigned short* Wc1  = (unsigned short*)alloc_b((size_t)2048 * 256 * 2);
    float*          bc1  = (float*)alloc_b(2048 * 4);
    unsigned short* Wc2  = (unsigned short*)alloc_b((size_t)1024 * 512 * 2);
    float*          bc2  = (float*)alloc_b(1024 * 4);
    unsigned short* Wc3  = (unsigned short*)alloc_b((size_t)512 * 256 * 2);
    float*          bc3  = (float*)alloc_b(512 * 4);
    unsigned short* QKVS = (unsigned short*)alloc_b((size_t)NN * 2048 * 2);
    unsigned short* H1   = (unsigned short*)alloc_b((size_t)NN * 512 * 2);
    unsigned short* H2   = (unsigned short*)alloc_b((size_t)NN * 256 * 2);
    unsigned short* H3   = (unsigned short*)alloc_b((size_t)NN * 128 * 2);
    int*   basep  = (int*)alloc_b((NN + 1) * 4);
    int*   csrc   = (int*)alloc_b((size_t)EE * 4);
    float* cea    = (float*)alloc_b((size_t)EE * 4);
    int*   gstart = (int*)alloc_b((GG + 1) * 4);
    size_t zstart = off;
    int*   deg    = (int*)alloc_b(NN * 4);
    int*   cnt    = (int*)alloc_b(NN * 4);
    size_t zbytes = off - zstart;

    if (ws_size < off) {
        ws_fail_k<<<(out_size + 255) / 256, 256, 0, stream>>>((float*)d_out, out_size);
        return;
    }

    hipMemsetAsync(wsb + zstart, 0, zbytes, stream);

    // ---- prep descriptors
    PrepArgs pa;
    int blk = 0, di = 0;
    auto add = [&](const float* src, void* dst, int rows, int cols, int mode) {
        pa.d[di].src = src; pa.d[di].dst = dst;
        pa.d[di].rows = rows; pa.d[di].cols = cols;
        pa.d[di].mode = mode; pa.d[di].blk0 = blk;
        blk += (rows * cols + 1023) / 1024;
        di++;
    };
    add(x, xb, NN * 256, 1, 0);
    for (int s = 0; s < 4; s++) add(W1[s], Wc1 + (size_t)s * 512 * 256, 256, 512, 1);
    for (int s = 0; s < 4; s++) add(B1[s], bc1 + s * 512, 512, 1, 2);
    for (int s = 0; s < 4; s++) add(W2[s], Wc2 + (size_t)s * 256 * 512, 512, 256, 1);
    for (int s = 0; s < 4; s++) add(B2[s], bc2 + s * 256, 256, 1, 2);
    for (int s = 0; s < 4; s++) add(W3[s], Wc3 + (size_t)s * 128 * 256, 256, 128, 1);
    for (int s = 0; s < 4; s++) add(B3[s], bc3 + s * 128, 128, 1, 2);
    prep_k<<<blk, 256, 0, stream>>>(pa);

    int eblocks = (EE + 255) / 256;
    count_deg_k<<<eblocks, 256, 0, stream>>>(ei, deg);
    scan_excl_k<<<1, 1024, 0, stream>>>(deg, basep, NN);
    fill_csr_k<<<eblocks, 256, 0, stream>>>(ei, ea, basep, cnt, csrc, cea);
    gbound_k<<<(NN + 255) / 256, 256, 0, stream>>>(bat, gstart);

    int mblocks = (NN + 127) / 128;
    // ---- layer 1: x[30000,256] -> QKVS[30000,2048]
    gemm_bf16_k<<<dim3(2048 / 128, mblocks), 256, 0, stream>>>(xb, Wc1, bc1, QKVS, NN, 256, 2048);
    aggregate_k<8, 64, true><<<NN / 4, 256, 0, stream>>>(QKVS, 2048, e1w, basep, csrc, cea, H1);
    // ---- layer 2: H1[30000,512] -> QKVS[30000,1024]
    gemm_bf16_k<<<dim3(1024 / 128, mblocks), 256, 0, stream>>>(H1, Wc2, bc2, QKVS, NN, 512, 1024);
    aggregate_k<4, 64, true><<<NN / 4, 256, 0, stream>>>(QKVS, 1024, e2w, basep, csrc, cea, H2);
    // ---- layer 3: H2[30000,256] -> QKVS[30000,512]
    gemm_bf16_k<<<dim3(512 / 128, mblocks), 256, 0, stream>>>(H2, Wc3, bc3, QKVS, NN, 256, 512);
    aggregate_k<1, 128, false><<<NN / 4, 256, 0, stream>>>(QKVS, 512, e3w, basep, csrc, cea, H3);

    // ---- fused pool + head
    pool_head_k<<<GG, 256, 0, stream>>>(H3, gstart, lw, lb, (float*)d_out);
}

// Round 5
// 823.890 us; speedup vs baseline: 2.9944x; 1.0373x over previous
//
#include <hip/hip_runtime.h>
#include <hip/hip_bf16.h>
#include <cstdint>

#define NN 30000
#define EE 480000
#define GG 64

typedef __attribute__((ext_vector_type(8))) short bf16x8;
typedef __attribute__((ext_vector_type(4))) float float4v;
typedef __attribute__((ext_vector_type(4))) unsigned short ushort4v;

static __device__ inline unsigned short f2bf(float f) {
    unsigned u = __float_as_uint(f);
    unsigned r = (u + 0x7fff + ((u >> 16) & 1)) >> 16;   // RNE
    return (unsigned short)r;
}
static __device__ inline float bf2f(unsigned short u) {
    return __uint_as_float(((unsigned)u) << 16);
}

// ---------------------------------------------------------------- CSR build
__global__ void count_deg_k(const int* __restrict__ ei, int* __restrict__ deg) {
    int e = blockIdx.x * 256 + threadIdx.x;
    if (e < EE) atomicAdd(&deg[ei[EE + e]], 1);
}

// 1 block, 1024 threads; each thread scans CH contiguous elems, one LDS tree.
__global__ __launch_bounds__(1024) void scan_excl_k(const int* __restrict__ deg,
                                                    int* __restrict__ basep) {
    constexpr int CH = (NN + 1024) / 1024 + 1;   // 30: 1024*30=30720 > 30000
    __shared__ int buf[1024];
    int t = threadIdx.x;
    int b0 = t * CH;
    int loc[CH];
    int s = 0;
#pragma unroll
    for (int i = 0; i < CH; i++) {
        int idx = b0 + i;
        int v = (idx < NN) ? deg[idx] : 0;
        loc[i] = s;
        s += v;
    }
    buf[t] = s;
    __syncthreads();
    for (int off = 1; off < 1024; off <<= 1) {
        int tv = (t >= off) ? buf[t - off] : 0;
        __syncthreads();
        buf[t] += tv;
        __syncthreads();
    }
    int base = (t > 0) ? buf[t - 1] : 0;
#pragma unroll
    for (int i = 0; i < CH; i++) {
        int idx = b0 + i;
        if (idx <= NN) basep[idx] = base + loc[i];
    }
}

__global__ void fill_csr_k(const int* __restrict__ ei, const float* __restrict__ ea,
                           const int* __restrict__ basep, int* __restrict__ cnt,
                           int* __restrict__ csrc, float* __restrict__ cea) {
    int e = blockIdx.x * 256 + threadIdx.x;
    if (e < EE) {
        int d = ei[EE + e];
        int pos = basep[d] + atomicAdd(&cnt[d], 1);
        csrc[pos] = ei[e];
        cea[pos] = ea[e];
    }
}

// batch is sorted: group start offsets
__global__ void gbound_k(const int* __restrict__ batch, int* __restrict__ gstart) {
    int i = blockIdx.x * 256 + threadIdx.x;
    if (i >= NN) return;
    int cur = batch[i];
    if (i == 0) {
        for (int g = 0; g <= cur; ++g) gstart[g] = 0;
    } else {
        int prev = batch[i - 1];
        for (int g = prev + 1; g <= cur; ++g) gstart[g] = i;
    }
    if (i == NN - 1) {
        for (int g = cur + 1; g <= GG; ++g) gstart[g] = NN;
    }
}

// ---------------------------------------------------------------- prep
struct PrepDesc { const float* src; void* dst; int rows; int cols; int blk0; int mode; };
#define NDESC 25
struct PrepArgs { PrepDesc d[NDESC]; };

__global__ __launch_bounds__(256) void prep_k(PrepArgs args) {
    int b = blockIdx.x;
    PrepDesc dd = args.d[0];
#pragma unroll
    for (int i = 1; i < NDESC; i++)
        if (b >= args.d[i].blk0) dd = args.d[i];
    int rel = b - dd.blk0;
    int total = dd.rows * dd.cols;
    int base = rel * 1024 + threadIdx.x;
    if (dd.mode == 0) {
        unsigned short* dst = (unsigned short*)dd.dst;
        for (int j = 0; j < 4; j++) {
            int i = base + j * 256;
            if (i < total) dst[i] = f2bf(dd.src[i]);
        }
    } else if (dd.mode == 1) {
        unsigned short* dst = (unsigned short*)dd.dst;
        for (int j = 0; j < 4; j++) {
            int i = base + j * 256;
            if (i < total) {
                int n = i / dd.rows, k = i - n * dd.rows;
                dst[i] = f2bf(dd.src[(size_t)k * dd.cols + n]);
            }
        }
    } else {
        float* dst = (float*)dd.dst;
        for (int j = 0; j < 4; j++) {
            int i = base + j * 256;
            if (i < total) dst[i] = dd.src[i];
        }
    }
}

// ---------------------------------------------------------------- bf16 MFMA GEMM
// C[M][N] = A[M][K] @ Wt[N][K]^T + bias.  128x128 tile, BK=32, 256 thr (2x2 waves).
// Double-buffered LDS: stage tile t+1 while computing t; 1 barrier per K-step.
__global__ __launch_bounds__(256) void gemm_bf16_k(
    const unsigned short* __restrict__ A, const unsigned short* __restrict__ Wt,
    const float* __restrict__ bias, unsigned short* __restrict__ C,
    int M, int K, int N) {
    __shared__ unsigned short As[2][4096];   // 8KB per buf
    __shared__ unsigned short Bs[2][4096];
    int tid = threadIdx.x;
    int lane = tid & 63, wid = tid >> 6;
    int wm = wid >> 1, wn = wid & 1;
    int row0 = blockIdx.y * 128, n0 = blockIdx.x * 128;

    float4v acc[4][4];
#pragma unroll
    for (int i = 0; i < 4; i++)
#pragma unroll
        for (int j = 0; j < 4; j++) acc[i][j] = (float4v)0.f;

    auto stage = [&](int buf, int k0) {
#pragma unroll
        for (int i = 0; i < 2; ++i) {
            int chunkbase = i * 256 + wid * 64;          // wave-uniform
            int chunk = chunkbase + lane;
            int r = chunk & 127, kc = chunk >> 7;
            int rowA = row0 + r; if (rowA >= M) rowA = M - 1;
            const unsigned short* ga = A + (size_t)rowA * K + (k0 + kc * 8);
            __builtin_amdgcn_global_load_lds(
                (const __attribute__((address_space(1))) void*)ga,
                (__attribute__((address_space(3))) void*)(As[buf] + (size_t)chunkbase * 8),
                16, 0, 0);
            const unsigned short* gb = Wt + (size_t)(n0 + r) * K + (k0 + kc * 8);
            __builtin_amdgcn_global_load_lds(
                (const __attribute__((address_space(1))) void*)gb,
                (__attribute__((address_space(3))) void*)(Bs[buf] + (size_t)chunkbase * 8),
                16, 0, 0);
        }
    };

    stage(0, 0);
    asm volatile("s_waitcnt vmcnt(0)" ::: "memory");
    __syncthreads();

    int NT = K >> 5;
    for (int t = 0; t < NT; ++t) {
        int b = t & 1;
        if (t + 1 < NT) stage(b ^ 1, (t + 1) << 5);
        bf16x8 af[4], bfr[4];
#pragma unroll
        for (int mi = 0; mi < 4; mi++)
            af[mi] = *(const bf16x8*)(As[b] + ((lane >> 4) * 128 + wm * 64 + mi * 16 + (lane & 15)) * 8);
#pragma unroll
        for (int ni = 0; ni < 4; ni++)
            bfr[ni] = *(const bf16x8*)(Bs[b] + ((lane >> 4) * 128 + wn * 64 + ni * 16 + (lane & 15)) * 8);
#pragma unroll
        for (int mi = 0; mi < 4; mi++)
#pragma unroll
            for (int ni = 0; ni < 4; ni++)
                acc[mi][ni] = __builtin_amdgcn_mfma_f32_16x16x32_bf16(
                    bfr[ni], af[mi], acc[mi][ni], 0, 0, 0);
        asm volatile("s_waitcnt vmcnt(0)" ::: "memory");
        __syncthreads();
    }

    float4v bias4[4];
#pragma unroll
    for (int ni = 0; ni < 4; ni++)
        bias4[ni] = *(const float4v*)&bias[n0 + wn * 64 + ni * 16 + (lane >> 4) * 4];
#pragma unroll
    for (int mi = 0; mi < 4; mi++) {
        int row = row0 + wm * 64 + mi * 16 + (lane & 15);
        if (row < M) {
#pragma unroll
            for (int ni = 0; ni < 4; ni++) {
                int colb = n0 + wn * 64 + ni * 16 + (lane >> 4) * 4;
                ushort4v pk;
#pragma unroll
                for (int r = 0; r < 4; r++) pk[r] = f2bf(acc[mi][ni][r] + bias4[ni][r]);
                *(ushort4v*)(C + (size_t)row * N + colb) = pk;
            }
        }
    }
}

// ---------------------------------------------------------------- aggregate
template <int VEC>
__device__ inline void loadbf(const unsigned short* __restrict__ p, float (&r)[VEC]) {
    if constexpr (VEC == 2) {
        unsigned v = *(const unsigned*)p;
        r[0] = __uint_as_float(v << 16);
        r[1] = __uint_as_float(v & 0xffff0000u);
    } else if constexpr (VEC == 4) {
        uint2 v = *(const uint2*)p;
        r[0] = __uint_as_float(v.x << 16); r[1] = __uint_as_float(v.x & 0xffff0000u);
        r[2] = __uint_as_float(v.y << 16); r[3] = __uint_as_float(v.y & 0xffff0000u);
    } else {
        uint4 v = *(const uint4*)p;
        r[0] = __uint_as_float(v.x << 16); r[1] = __uint_as_float(v.x & 0xffff0000u);
        r[2] = __uint_as_float(v.y << 16); r[3] = __uint_as_float(v.y & 0xffff0000u);
        r[4] = __uint_as_float(v.z << 16); r[5] = __uint_as_float(v.z & 0xffff0000u);
        r[6] = __uint_as_float(v.w << 16); r[7] = __uint_as_float(v.w & 0xffff0000u);
    }
}
template <int VEC>
__device__ inline void loadf32(const float* __restrict__ p, float (&r)[VEC]) {
    if constexpr (VEC == 2) {
        float2 t = *reinterpret_cast<const float2*>(p);
        r[0] = t.x; r[1] = t.y;
    } else {
#pragma unroll
        for (int i = 0; i < VEC; i += 4) {
            float4 t = *reinterpret_cast<const float4*>(p + i);
            r[i] = t.x; r[i + 1] = t.y; r[i + 2] = t.z; r[i + 3] = t.w;
        }
    }
}
template <int VEC>
__device__ inline void storebf(unsigned short* __restrict__ p, const float (&r)[VEC]) {
    unsigned w[VEC / 2];
#pragma unroll
    for (int i = 0; i < VEC / 2; i++)
        w[i] = (unsigned)f2bf(r[2 * i]) | ((unsigned)f2bf(r[2 * i + 1]) << 16);
    if constexpr (VEC == 2) *(unsigned*)p = w[0];
    else if constexpr (VEC == 4) *(uint2*)p = make_uint2(w[0], w[1]);
    else *(uint4*)p = make_uint4(w[0], w[1], w[2], w[3]);
}

// One wave per node. QKVS row: [Q | K | V | S], stride SR = 4F bf16.
// 2-deep register pipeline; max-free softmax (scores are O(1): exp(min(s,30))).
template <int H, int D, bool RELU>
__global__ __launch_bounds__(256) void aggregate_k(
    const unsigned short* __restrict__ QKVS, int SR,
    const float* __restrict__ ew,
    const int* __restrict__ rowptr, const int* __restrict__ csrc,
    const float* __restrict__ cea, unsigned short* __restrict__ Hout) {
    constexpr int F = H * D;
    constexpr int VEC = F / 64;
    constexpr int L = 64 / H;
    int lane = threadIdx.x & 63;
    int node = blockIdx.x * 4 + (threadIdx.x >> 6);
    if (node >= NN) return;

    const unsigned short* qrow = QKVS + (size_t)node * SR;
    float q[VEC], ewv[VEC], acc[VEC];
    loadbf<VEC>(qrow + lane * VEC, q);
    loadf32<VEC>(ew + lane * VEC, ewv);
#pragma unroll
    for (int i = 0; i < VEC; i++) acc[i] = 0.f;

    float den = 0.f;
    const float isd = rsqrtf((float)D);
    int beg = rowptr[node], end = rowptr[node + 1];

    float kA[VEC], vA[VEC], eA = 0.f;
    float kB[VEC], vB[VEC], eB = 0.f;
    if (beg < end) {
        int s = csrc[beg]; eA = cea[beg];
        const unsigned short* b = QKVS + (size_t)s * SR + F;
        loadbf<VEC>(b + lane * VEC, kA);
        loadbf<VEC>(b + F + lane * VEC, vA);
    }
    if (beg + 1 < end) {
        int s = csrc[beg + 1]; eB = cea[beg + 1];
        const unsigned short* b = QKVS + (size_t)s * SR + F;
        loadbf<VEC>(b + lane * VEC, kB);
        loadbf<VEC>(b + F + lane * VEC, vB);
    }

    for (int j = beg; j < end; j += 2) {
        {   // process A (edge j)
            float t[VEC], p = 0.f;
#pragma unroll
            for (int i = 0; i < VEC; i++) { t[i] = eA * ewv[i]; p += q[i] * (kA[i] + t[i]); }
#pragma unroll
            for (int off = 1; off < L; off <<= 1) p += __shfl_xor(p, off, 64);
            float w = __expf(fminf(p * isd, 30.f));
            den += w;
#pragma unroll
            for (int i = 0; i < VEC; i++) acc[i] += w * (vA[i] + t[i]);
        }
        if (j + 2 < end) {   // prefetch A <- j+2
            int s = csrc[j + 2]; eA = cea[j + 2];
            const unsigned short* b = QKVS + (size_t)s * SR + F;
            loadbf<VEC>(b + lane * VEC, kA);
            loadbf<VEC>(b + F + lane * VEC, vA);
        }
        if (j + 1 < end) {   // process B (edge j+1)
            float t[VEC], p = 0.f;
#pragma unroll
            for (int i = 0; i < VEC; i++) { t[i] = eB * ewv[i]; p += q[i] * (kB[i] + t[i]); }
#pragma unroll
            for (int off = 1; off < L; off <<= 1) p += __shfl_xor(p, off, 64);
            float w = __expf(fminf(p * isd, 30.f));
            den += w;
#pragma unroll
            for (int i = 0; i < VEC; i++) acc[i] += w * (vB[i] + t[i]);
        }
        if (j + 3 < end) {   // prefetch B <- j+3
            int s = csrc[j + 3]; eB = cea[j + 3];
            const unsigned short* b = QKVS + (size_t)s * SR + F;
            loadbf<VEC>(b + lane * VEC, kB);
            loadbf<VEC>(b + F + lane * VEC, vB);
        }
    }

    float rden = (den > 0.f) ? 1.f / den : 0.f;
    float sv[VEC];
    loadbf<VEC>(qrow + 3 * F + lane * VEC, sv);
    float o[VEC];
#pragma unroll
    for (int i = 0; i < VEC; i++) {
        float v = acc[i] * rden + sv[i];
        o[i] = RELU ? fmaxf(v, 0.f) : v;
    }
    storebf<VEC>(Hout + (size_t)node * F + lane * VEC, o);
}

// ---------------------------------------------------------------- pool+head (fused)
__global__ __launch_bounds__(256) void pool_head_k(
    const unsigned short* __restrict__ h3, const int* __restrict__ gstart,
    const float* __restrict__ lw, const float* __restrict__ lb,
    float* __restrict__ out) {
    __shared__ float part[256];
    __shared__ float pooled[128];
    int g = blockIdx.x;
    int beg = gstart[g], end = gstart[g + 1];
    int d = threadIdx.x & 127, half = threadIdx.x >> 7;
    float s = 0.f;
    for (int node = beg + half; node < end; node += 2)
        s += bf2f(h3[(size_t)node * 128 + d]);
    part[threadIdx.x] = s;
    __syncthreads();
    if (threadIdx.x < 128) {
        float cnt = fmaxf((float)(end - beg), 1.0f);
        pooled[threadIdx.x] = (part[threadIdx.x] + part[threadIdx.x + 128]) / cnt;
    }
    __syncthreads();
    if (threadIdx.x < 13) {
        float acc = lb[threadIdx.x];
        for (int dd = 0; dd < 128; ++dd)
            acc += pooled[dd] * lw[dd * 13 + threadIdx.x];
        out[g * 13 + threadIdx.x] = acc;
    }
}

__global__ void ws_fail_k(float* __restrict__ out, int n) {
    int i = blockIdx.x * 256 + threadIdx.x;
    if (i < n) out[i] = -12345.0f;
}

// ---------------------------------------------------------------- launch
extern "C" void kernel_launch(void* const* d_in, const int* in_sizes, int n_in,
                              void* d_out, int out_size, void* d_ws, size_t ws_size,
                              hipStream_t stream) {
    const float* x   = (const float*)d_in[0];
    const int*   ei  = (const int*)d_in[1];
    const float* ea  = (const float*)d_in[2];
    const int*   bat = (const int*)d_in[3];
    const float* W1[4] = {(const float*)d_in[4], (const float*)d_in[6], (const float*)d_in[8], (const float*)d_in[11]};
    const float* B1[4] = {(const float*)d_in[5], (const float*)d_in[7], (const float*)d_in[9], (const float*)d_in[12]};
    const float* e1w = (const float*)d_in[10];
    const float* W2[4] = {(const float*)d_in[13], (const float*)d_in[15], (const float*)d_in[17], (const float*)d_in[20]};
    const float* B2[4] = {(const float*)d_in[14], (const float*)d_in[16], (const float*)d_in[18], (const float*)d_in[21]};
    const float* e2w = (const float*)d_in[19];
    const float* W3[4] = {(const float*)d_in[22], (const float*)d_in[24], (const float*)d_in[26], (const float*)d_in[29]};
    const float* B3[4] = {(const float*)d_in[23], (const float*)d_in[25], (const float*)d_in[27], (const float*)d_in[30]};
    const float* e3w = (const float*)d_in[28];
    const float* lw  = (const float*)d_in[31];
    const float* lb  = (const float*)d_in[32];

    char* wsb = (char*)d_ws;
    size_t off = 0;
    auto alloc_b = [&](size_t bytes) {
        void* p = wsb + off;
        off += (bytes + 255) & ~(size_t)255;
        return p;
    };
    unsigned short* xb   = (unsigned short*)alloc_b((size_t)NN * 256 * 2);
    unsigned short* Wc1  = (unsigned short*)alloc_b((size_t)2048 * 256 * 2);
    float*          bc1  = (float*)alloc_b(2048 * 4);
    unsigned short* Wc2  = (unsigned short*)alloc_b((size_t)1024 * 512 * 2);
    float*          bc2  = (float*)alloc_b(1024 * 4);
    unsigned short* Wc3  = (unsigned short*)alloc_b((size_t)512 * 256 * 2);
    float*          bc3  = (float*)alloc_b(512 * 4);
    unsigned short* QKVS = (unsigned short*)alloc_b((size_t)NN * 2048 * 2);
    unsigned short* H1   = (unsigned short*)alloc_b((size_t)NN * 512 * 2);
    unsigned short* H2   = (unsigned short*)alloc_b((size_t)NN * 256 * 2);
    unsigned short* H3   = (unsigned short*)alloc_b((size_t)NN * 128 * 2);
    int*   basep  = (int*)alloc_b((NN + 1) * 4);
    int*   csrc   = (int*)alloc_b((size_t)EE * 4);
    float* cea    = (float*)alloc_b((size_t)EE * 4);
    int*   gstart = (int*)alloc_b((GG + 1) * 4);
    size_t zstart = off;
    int*   deg    = (int*)alloc_b(NN * 4);
    int*   cnt    = (int*)alloc_b(NN * 4);
    size_t zbytes = off - zstart;

    if (ws_size < off) {
        ws_fail_k<<<(out_size + 255) / 256, 256, 0, stream>>>((float*)d_out, out_size);
        return;
    }

    hipMemsetAsync(wsb + zstart, 0, zbytes, stream);

    PrepArgs pa;
    int blk = 0, di = 0;
    auto add = [&](const float* src, void* dst, int rows, int cols, int mode) {
        pa.d[di].src = src; pa.d[di].dst = dst;
        pa.d[di].rows = rows; pa.d[di].cols = cols;
        pa.d[di].mode = mode; pa.d[di].blk0 = blk;
        blk += (rows * cols + 1023) / 1024;
        di++;
    };
    add(x, xb, NN * 256, 1, 0);
    for (int s = 0; s < 4; s++) add(W1[s], Wc1 + (size_t)s * 512 * 256, 256, 512, 1);
    for (int s = 0; s < 4; s++) add(B1[s], bc1 + s * 512, 512, 1, 2);
    for (int s = 0; s < 4; s++) add(W2[s], Wc2 + (size_t)s * 256 * 512, 512, 256, 1);
    for (int s = 0; s < 4; s++) add(B2[s], bc2 + s * 256, 256, 1, 2);
    for (int s = 0; s < 4; s++) add(W3[s], Wc3 + (size_t)s * 128 * 256, 256, 128, 1);
    for (int s = 0; s < 4; s++) add(B3[s], bc3 + s * 128, 128, 1, 2);
    prep_k<<<blk, 256, 0, stream>>>(pa);

    int eblocks = (EE + 255) / 256;
    count_deg_k<<<eblocks, 256, 0, stream>>>(ei, deg);
    scan_excl_k<<<1, 1024, 0, stream>>>(deg, basep);
    fill_csr_k<<<eblocks, 256, 0, stream>>>(ei, ea, basep, cnt, csrc, cea);
    gbound_k<<<(NN + 255) / 256, 256, 0, stream>>>(bat, gstart);

    int mblocks = (NN + 127) / 128;
    // ---- layer 1: x[30000,256] -> QKVS[30000,2048]
    gemm_bf16_k<<<dim3(2048 / 128, mblocks), 256, 0, stream>>>(xb, Wc1, bc1, QKVS, NN, 256, 2048);
    aggregate_k<8, 64, true><<<NN / 4, 256, 0, stream>>>(QKVS, 2048, e1w, basep, csrc, cea, H1);
    // ---- layer 2: H1[30000,512] -> QKVS[30000,1024]
    gemm_bf16_k<<<dim3(1024 / 128, mblocks), 256, 0, stream>>>(H1, Wc2, bc2, QKVS, NN, 512, 1024);
    aggregate_k<4, 64, true><<<NN / 4, 256, 0, stream>>>(QKVS, 1024, e2w, basep, csrc, cea, H2);
    // ---- layer 3: H2[30000,256] -> QKVS[30000,512]
    gemm_bf16_k<<<dim3(512 / 128, mblocks), 256, 0, stream>>>(H2, Wc3, bc3, QKVS, NN, 256, 512);
    aggregate_k<1, 128, false><<<NN / 4, 256, 0, stream>>>(QKVS, 512, e3w, basep, csrc, cea, H3);

    // ---- fused pool + head
    pool_head_k<<<GG, 256, 0, stream>>>(H3, gstart, lw, lb, (float*)d_out);
}

// Round 6
// 793.904 us; speedup vs baseline: 3.1075x; 1.0378x over previous
//
#include <hip/hip_runtime.h>
#include <hip/hip_bf16.h>
#include <cstdint>

#define NN 30000
#define EE 480000
#define GG 64

typedef __attribute__((ext_vector_type(8))) short bf16x8;
typedef __attribute__((ext_vector_type(4))) float float4v;
typedef __attribute__((ext_vector_type(4))) unsigned short ushort4v;

static __device__ inline unsigned short f2bf(float f) {
    unsigned u = __float_as_uint(f);
    unsigned r = (u + 0x7fff + ((u >> 16) & 1)) >> 16;   // RNE
    return (unsigned short)r;
}
static __device__ inline float bf2f(unsigned short u) {
    return __uint_as_float(((unsigned)u) << 16);
}

// ---------------------------------------------------------------- CSR build
__global__ void count_deg_k(const int* __restrict__ ei, int* __restrict__ deg) {
    int e = blockIdx.x * 256 + threadIdx.x;
    if (e < EE) atomicAdd(&deg[ei[EE + e]], 1);
}

// 1 block, 1024 threads; each thread scans CH contiguous elems, one LDS tree.
__global__ __launch_bounds__(1024) void scan_excl_k(const int* __restrict__ deg,
                                                    int* __restrict__ basep) {
    constexpr int CH = (NN + 1024) / 1024 + 1;   // 30
    __shared__ int buf[1024];
    int t = threadIdx.x;
    int b0 = t * CH;
    int loc[CH];
    int s = 0;
#pragma unroll
    for (int i = 0; i < CH; i++) {
        int idx = b0 + i;
        int v = (idx < NN) ? deg[idx] : 0;
        loc[i] = s;
        s += v;
    }
    buf[t] = s;
    __syncthreads();
    for (int off = 1; off < 1024; off <<= 1) {
        int tv = (t >= off) ? buf[t - off] : 0;
        __syncthreads();
        buf[t] += tv;
        __syncthreads();
    }
    int base = (t > 0) ? buf[t - 1] : 0;
#pragma unroll
    for (int i = 0; i < CH; i++) {
        int idx = b0 + i;
        if (idx <= NN) basep[idx] = base + loc[i];
    }
}

__global__ void fill_csr_k(const int* __restrict__ ei, const float* __restrict__ ea,
                           const int* __restrict__ basep, int* __restrict__ cnt,
                           int* __restrict__ csrc, float* __restrict__ cea) {
    int e = blockIdx.x * 256 + threadIdx.x;
    if (e < EE) {
        int d = ei[EE + e];
        int pos = basep[d] + atomicAdd(&cnt[d], 1);
        csrc[pos] = ei[e];
        cea[pos] = ea[e];
    }
}

// batch is sorted: group start offsets
__global__ void gbound_k(const int* __restrict__ batch, int* __restrict__ gstart) {
    int i = blockIdx.x * 256 + threadIdx.x;
    if (i >= NN) return;
    int cur = batch[i];
    if (i == 0) {
        for (int g = 0; g <= cur; ++g) gstart[g] = 0;
    } else {
        int prev = batch[i - 1];
        for (int g = prev + 1; g <= cur; ++g) gstart[g] = i;
    }
    if (i == NN - 1) {
        for (int g = cur + 1; g <= GG; ++g) gstart[g] = NN;
    }
}

// ---------------------------------------------------------------- prep
struct PrepDesc { const float* src; void* dst; int rows; int cols; int blk0; int mode; };
#define NDESC 25
struct PrepArgs { PrepDesc d[NDESC]; };

__global__ __launch_bounds__(256) void prep_k(PrepArgs args) {
    int b = blockIdx.x;
    PrepDesc dd = args.d[0];
#pragma unroll
    for (int i = 1; i < NDESC; i++)
        if (b >= args.d[i].blk0) dd = args.d[i];
    int rel = b - dd.blk0;
    int total = dd.rows * dd.cols;
    int base = rel * 1024 + threadIdx.x;
    if (dd.mode == 0) {
        unsigned short* dst = (unsigned short*)dd.dst;
        for (int j = 0; j < 4; j++) {
            int i = base + j * 256;
            if (i < total) dst[i] = f2bf(dd.src[i]);
        }
    } else if (dd.mode == 1) {
        unsigned short* dst = (unsigned short*)dd.dst;
        for (int j = 0; j < 4; j++) {
            int i = base + j * 256;
            if (i < total) {
                int n = i / dd.rows, k = i - n * dd.rows;
                dst[i] = f2bf(dd.src[(size_t)k * dd.cols + n]);
            }
        }
    } else {
        float* dst = (float*)dd.dst;
        for (int j = 0; j < 4; j++) {
            int i = base + j * 256;
            if (i < total) dst[i] = dd.src[i];
        }
    }
}

// ---------------------------------------------------------------- bf16 MFMA GEMM
// C[M][N] = A[M][K] @ Wt[N][K]^T + bias.  128x128 tile, BK=32, dbuf LDS,
// bijective XCD swizzle (contiguous tile range per XCD -> A-panel L2 reuse).
__global__ __launch_bounds__(256) void gemm_bf16_k(
    const unsigned short* __restrict__ A, const unsigned short* __restrict__ Wt,
    const float* __restrict__ bias, unsigned short* __restrict__ C,
    int M, int K, int N) {
    __shared__ unsigned short As[2][4096];
    __shared__ unsigned short Bs[2][4096];
    int tid = threadIdx.x;
    int lane = tid & 63, wid = tid >> 6;
    int wm = wid >> 1, wn = wid & 1;

    // bijective XCD-aware remap of linear block id (m204)
    int gx = gridDim.x;
    int T = gx * gridDim.y;
    int lid = blockIdx.y * gx + blockIdx.x;
    int qq = T >> 3, rr = T & 7;
    int xcd = lid & 7, pos = lid >> 3;
    int tile = ((xcd < rr) ? xcd * (qq + 1) : rr * (qq + 1) + (xcd - rr) * qq) + pos;
    int by = tile / gx, bx = tile - by * gx;
    int row0 = by * 128, n0 = bx * 128;

    float4v acc[4][4];
#pragma unroll
    for (int i = 0; i < 4; i++)
#pragma unroll
        for (int j = 0; j < 4; j++) acc[i][j] = (float4v)0.f;

    auto stage = [&](int buf, int k0) {
#pragma unroll
        for (int i = 0; i < 2; ++i) {
            int chunkbase = i * 256 + wid * 64;          // wave-uniform
            int chunk = chunkbase + lane;
            int r = chunk & 127, kc = chunk >> 7;
            int rowA = row0 + r; if (rowA >= M) rowA = M - 1;
            const unsigned short* ga = A + (size_t)rowA * K + (k0 + kc * 8);
            __builtin_amdgcn_global_load_lds(
                (const __attribute__((address_space(1))) void*)ga,
                (__attribute__((address_space(3))) void*)(As[buf] + (size_t)chunkbase * 8),
                16, 0, 0);
            const unsigned short* gb = Wt + (size_t)(n0 + r) * K + (k0 + kc * 8);
            __builtin_amdgcn_global_load_lds(
                (const __attribute__((address_space(1))) void*)gb,
                (__attribute__((address_space(3))) void*)(Bs[buf] + (size_t)chunkbase * 8),
                16, 0, 0);
        }
    };

    stage(0, 0);
    asm volatile("s_waitcnt vmcnt(0)" ::: "memory");
    __syncthreads();

    int NT = K >> 5;
    for (int t = 0; t < NT; ++t) {
        int b = t & 1;
        if (t + 1 < NT) stage(b ^ 1, (t + 1) << 5);
        bf16x8 af[4], bfr[4];
#pragma unroll
        for (int mi = 0; mi < 4; mi++)
            af[mi] = *(const bf16x8*)(As[b] + ((lane >> 4) * 128 + wm * 64 + mi * 16 + (lane & 15)) * 8);
#pragma unroll
        for (int ni = 0; ni < 4; ni++)
            bfr[ni] = *(const bf16x8*)(Bs[b] + ((lane >> 4) * 128 + wn * 64 + ni * 16 + (lane & 15)) * 8);
#pragma unroll
        for (int mi = 0; mi < 4; mi++)
#pragma unroll
            for (int ni = 0; ni < 4; ni++)
                acc[mi][ni] = __builtin_amdgcn_mfma_f32_16x16x32_bf16(
                    bfr[ni], af[mi], acc[mi][ni], 0, 0, 0);
        asm volatile("s_waitcnt vmcnt(0)" ::: "memory");
        __syncthreads();
    }

    float4v bias4[4];
#pragma unroll
    for (int ni = 0; ni < 4; ni++)
        bias4[ni] = *(const float4v*)&bias[n0 + wn * 64 + ni * 16 + (lane >> 4) * 4];
#pragma unroll
    for (int mi = 0; mi < 4; mi++) {
        int row = row0 + wm * 64 + mi * 16 + (lane & 15);
        if (row < M) {
#pragma unroll
            for (int ni = 0; ni < 4; ni++) {
                int colb = n0 + wn * 64 + ni * 16 + (lane >> 4) * 4;
                ushort4v pk;
#pragma unroll
                for (int r = 0; r < 4; r++) pk[r] = f2bf(acc[mi][ni][r] + bias4[ni][r]);
                *(ushort4v*)(C + (size_t)row * N + colb) = pk;
            }
        }
    }
}

// ---------------------------------------------------------------- aggregate
template <int VEC> struct RawVec;
template <> struct RawVec<2> { using T = unsigned; };
template <> struct RawVec<4> { using T = uint2; };
template <> struct RawVec<8> { using T = uint4; };

static __device__ inline void unpackr(unsigned v, float (&r)[2]) {
    r[0] = __uint_as_float(v << 16); r[1] = __uint_as_float(v & 0xffff0000u);
}
static __device__ inline void unpackr(uint2 v, float (&r)[4]) {
    r[0] = __uint_as_float(v.x << 16); r[1] = __uint_as_float(v.x & 0xffff0000u);
    r[2] = __uint_as_float(v.y << 16); r[3] = __uint_as_float(v.y & 0xffff0000u);
}
static __device__ inline void unpackr(uint4 v, float (&r)[8]) {
    r[0] = __uint_as_float(v.x << 16); r[1] = __uint_as_float(v.x & 0xffff0000u);
    r[2] = __uint_as_float(v.y << 16); r[3] = __uint_as_float(v.y & 0xffff0000u);
    r[4] = __uint_as_float(v.z << 16); r[5] = __uint_as_float(v.z & 0xffff0000u);
    r[6] = __uint_as_float(v.w << 16); r[7] = __uint_as_float(v.w & 0xffff0000u);
}

template <int VEC>
__device__ inline void loadbf(const unsigned short* __restrict__ p, float (&r)[VEC]) {
    typename RawVec<VEC>::T v = *(const typename RawVec<VEC>::T*)p;
    unpackr(v, r);
}
template <int VEC>
__device__ inline void loadf32(const float* __restrict__ p, float (&r)[VEC]) {
    if constexpr (VEC == 2) {
        float2 t = *reinterpret_cast<const float2*>(p);
        r[0] = t.x; r[1] = t.y;
    } else {
#pragma unroll
        for (int i = 0; i < VEC; i += 4) {
            float4 t = *reinterpret_cast<const float4*>(p + i);
            r[i] = t.x; r[i + 1] = t.y; r[i + 2] = t.z; r[i + 3] = t.w;
        }
    }
}
template <int VEC>
__device__ inline void storebf(unsigned short* __restrict__ p, const float (&r)[VEC]) {
    unsigned w[VEC / 2];
#pragma unroll
    for (int i = 0; i < VEC / 2; i++)
        w[i] = (unsigned)f2bf(r[2 * i]) | ((unsigned)f2bf(r[2 * i + 1]) << 16);
    if constexpr (VEC == 2) *(unsigned*)p = w[0];
    else if constexpr (VEC == 4) *(uint2*)p = make_uint2(w[0], w[1]);
    else *(uint4*)p = make_uint4(w[0], w[1], w[2], w[3]);
}

// One wave per node. QKVS row: [Q | K | V | S], stride SR = 4F bf16.
// 4-deep packed-register prefetch pipeline; max-free softmax.
template <int H, int D, bool RELU>
__global__ __launch_bounds__(256) void aggregate_k(
    const unsigned short* __restrict__ QKVS, int SR,
    const float* __restrict__ ew,
    const int* __restrict__ rowptr, const int* __restrict__ csrc,
    const float* __restrict__ cea, unsigned short* __restrict__ Hout) {
    constexpr int F = H * D;
    constexpr int VEC = F / 64;
    constexpr int L = 64 / H;
    using RawT = typename RawVec<VEC>::T;
    int lane = threadIdx.x & 63;
    int node = blockIdx.x * 4 + (threadIdx.x >> 6);
    if (node >= NN) return;

    const unsigned short* qrow = QKVS + (size_t)node * SR;
    float q[VEC], ewv[VEC], acc[VEC];
    loadbf<VEC>(qrow + lane * VEC, q);
    loadf32<VEC>(ew + lane * VEC, ewv);
#pragma unroll
    for (int i = 0; i < VEC; i++) acc[i] = 0.f;

    float den = 0.f;
    const float isd = rsqrtf((float)D);
    int beg = rowptr[node], end = rowptr[node + 1];

    RawT k0r, k1r, k2r, k3r, v0r, v1r, v2r, v3r;
    float e0, e1, e2, e3;
    auto fetch = [&](int j, RawT& kr, RawT& vr, float& ea) {
        int s = csrc[j]; ea = cea[j];
        const unsigned short* b = QKVS + (size_t)s * SR + F + lane * VEC;
        kr = *(const RawT*)b;
        vr = *(const RawT*)(b + F);
    };
    auto process = [&](RawT kr, RawT vr, float ea) {
        float kv[VEC], vv[VEC], t[VEC];
        unpackr(kr, kv);
        unpackr(vr, vv);
        float p = 0.f;
#pragma unroll
        for (int i = 0; i < VEC; i++) { t[i] = ea * ewv[i]; p += q[i] * (kv[i] + t[i]); }
#pragma unroll
        for (int off = 1; off < L; off <<= 1) p += __shfl_xor(p, off, 64);
        float w = __expf(fminf(p * isd, 30.f));
        den += w;
#pragma unroll
        for (int i = 0; i < VEC; i++) acc[i] += w * (vv[i] + t[i]);
    };

    if (beg + 0 < end) fetch(beg + 0, k0r, v0r, e0);
    if (beg + 1 < end) fetch(beg + 1, k1r, v1r, e1);
    if (beg + 2 < end) fetch(beg + 2, k2r, v2r, e2);
    if (beg + 3 < end) fetch(beg + 3, k3r, v3r, e3);

    for (int j = beg; j < end; j += 4) {
        process(k0r, v0r, e0);
        if (j + 4 < end) fetch(j + 4, k0r, v0r, e0);
        if (j + 1 < end) {
            process(k1r, v1r, e1);
            if (j + 5 < end) fetch(j + 5, k1r, v1r, e1);
        }
        if (j + 2 < end) {
            process(k2r, v2r, e2);
            if (j + 6 < end) fetch(j + 6, k2r, v2r, e2);
        }
        if (j + 3 < end) {
            process(k3r, v3r, e3);
            if (j + 7 < end) fetch(j + 7, k3r, v3r, e3);
        }
    }

    float rden = (den > 0.f) ? 1.f / den : 0.f;
    float sv[VEC];
    loadbf<VEC>(qrow + 3 * F + lane * VEC, sv);
    float o[VEC];
#pragma unroll
    for (int i = 0; i < VEC; i++) {
        float v = acc[i] * rden + sv[i];
        o[i] = RELU ? fmaxf(v, 0.f) : v;
    }
    storebf<VEC>(Hout + (size_t)node * F + lane * VEC, o);
}

// ---------------------------------------------------------------- pool+head (fused)
__global__ __launch_bounds__(256) void pool_head_k(
    const unsigned short* __restrict__ h3, const int* __restrict__ gstart,
    const float* __restrict__ lw, const float* __restrict__ lb,
    float* __restrict__ out) {
    __shared__ float part[256];
    __shared__ float pooled[128];
    int g = blockIdx.x;
    int beg = gstart[g], end = gstart[g + 1];
    int d = threadIdx.x & 127, half = threadIdx.x >> 7;
    float s = 0.f;
    for (int node = beg + half; node < end; node += 2)
        s += bf2f(h3[(size_t)node * 128 + d]);
    part[threadIdx.x] = s;
    __syncthreads();
    if (threadIdx.x < 128) {
        float cnt = fmaxf((float)(end - beg), 1.0f);
        pooled[threadIdx.x] = (part[threadIdx.x] + part[threadIdx.x + 128]) / cnt;
    }
    __syncthreads();
    if (threadIdx.x < 13) {
        float acc = lb[threadIdx.x];
        for (int dd = 0; dd < 128; ++dd)
            acc += pooled[dd] * lw[dd * 13 + threadIdx.x];
        out[g * 13 + threadIdx.x] = acc;
    }
}

__global__ void ws_fail_k(float* __restrict__ out, int n) {
    int i = blockIdx.x * 256 + threadIdx.x;
    if (i < n) out[i] = -12345.0f;
}

// ---------------------------------------------------------------- launch
extern "C" void kernel_launch(void* const* d_in, const int* in_sizes, int n_in,
                              void* d_out, int out_size, void* d_ws, size_t ws_size,
                              hipStream_t stream) {
    const float* x   = (const float*)d_in[0];
    const int*   ei  = (const int*)d_in[1];
    const float* ea  = (const float*)d_in[2];
    const int*   bat = (const int*)d_in[3];
    const float* W1[4] = {(const float*)d_in[4], (const float*)d_in[6], (const float*)d_in[8], (const float*)d_in[11]};
    const float* B1[4] = {(const float*)d_in[5], (const float*)d_in[7], (const float*)d_in[9], (const float*)d_in[12]};
    const float* e1w = (const float*)d_in[10];
    const float* W2[4] = {(const float*)d_in[13], (const float*)d_in[15], (const float*)d_in[17], (const float*)d_in[20]};
    const float* B2[4] = {(const float*)d_in[14], (const float*)d_in[16], (const float*)d_in[18], (const float*)d_in[21]};
    const float* e2w = (const float*)d_in[19];
    const float* W3[4] = {(const float*)d_in[22], (const float*)d_in[24], (const float*)d_in[26], (const float*)d_in[29]};
    const float* B3[4] = {(const float*)d_in[23], (const float*)d_in[25], (const float*)d_in[27], (const float*)d_in[30]};
    const float* e3w = (const float*)d_in[28];
    const float* lw  = (const float*)d_in[31];
    const float* lb  = (const float*)d_in[32];

    char* wsb = (char*)d_ws;
    size_t off = 0;
    auto alloc_b = [&](size_t bytes) {
        void* p = wsb + off;
        off += (bytes + 255) & ~(size_t)255;
        return p;
    };
    unsigned short* xb   = (unsigned short*)alloc_b((size_t)NN * 256 * 2);
    unsigned short* Wc1  = (unsigned short*)alloc_b((size_t)2048 * 256 * 2);
    float*          bc1  = (float*)alloc_b(2048 * 4);
    unsigned short* Wc2  = (unsigned short*)alloc_b((size_t)1024 * 512 * 2);
    float*          bc2  = (float*)alloc_b(1024 * 4);
    unsigned short* Wc3  = (unsigned short*)alloc_b((size_t)512 * 256 * 2);
    float*          bc3  = (float*)alloc_b(512 * 4);
    unsigned short* QKVS = (unsigned short*)alloc_b((size_t)NN * 2048 * 2);
    unsigned short* H1   = (unsigned short*)alloc_b((size_t)NN * 512 * 2);
    unsigned short* H2   = (unsigned short*)alloc_b((size_t)NN * 256 * 2);
    unsigned short* H3   = (unsigned short*)alloc_b((size_t)NN * 128 * 2);
    int*   basep  = (int*)alloc_b((NN + 1) * 4);
    int*   csrc   = (int*)alloc_b((size_t)EE * 4);
    float* cea    = (float*)alloc_b((size_t)EE * 4);
    int*   gstart = (int*)alloc_b((GG + 1) * 4);
    size_t zstart = off;
    int*   deg    = (int*)alloc_b(NN * 4);
    int*   cnt    = (int*)alloc_b(NN * 4);
    size_t zbytes = off - zstart;

    if (ws_size < off) {
        ws_fail_k<<<(out_size + 255) / 256, 256, 0, stream>>>((float*)d_out, out_size);
        return;
    }

    hipMemsetAsync(wsb + zstart, 0, zbytes, stream);

    PrepArgs pa;
    int blk = 0, di = 0;
    auto add = [&](const float* src, void* dst, int rows, int cols, int mode) {
        pa.d[di].src = src; pa.d[di].dst = dst;
        pa.d[di].rows = rows; pa.d[di].cols = cols;
        pa.d[di].mode = mode; pa.d[di].blk0 = blk;
        blk += (rows * cols + 1023) / 1024;
        di++;
    };
    add(x, xb, NN * 256, 1, 0);
    for (int s = 0; s < 4; s++) add(W1[s], Wc1 + (size_t)s * 512 * 256, 256, 512, 1);
    for (int s = 0; s < 4; s++) add(B1[s], bc1 + s * 512, 512, 1, 2);
    for (int s = 0; s < 4; s++) add(W2[s], Wc2 + (size_t)s * 256 * 512, 512, 256, 1);
    for (int s = 0; s < 4; s++) add(B2[s], bc2 + s * 256, 256, 1, 2);
    for (int s = 0; s < 4; s++) add(W3[s], Wc3 + (size_t)s * 128 * 256, 256, 128, 1);
    for (int s = 0; s < 4; s++) add(B3[s], bc3 + s * 128, 128, 1, 2);
    prep_k<<<blk, 256, 0, stream>>>(pa);

    int eblocks = (EE + 255) / 256;
    count_deg_k<<<eblocks, 256, 0, stream>>>(ei, deg);
    scan_excl_k<<<1, 1024, 0, stream>>>(deg, basep);
    fill_csr_k<<<eblocks, 256, 0, stream>>>(ei, ea, basep, cnt, csrc, cea);
    gbound_k<<<(NN + 255) / 256, 256, 0, stream>>>(bat, gstart);

    int mblocks = (NN + 127) / 128;
    // ---- layer 1: x[30000,256] -> QKVS[30000,2048]
    gemm_bf16_k<<<dim3(2048 / 128, mblocks), 256, 0, stream>>>(xb, Wc1, bc1, QKVS, NN, 256, 2048);
    aggregate_k<8, 64, true><<<NN / 4, 256, 0, stream>>>(QKVS, 2048, e1w, basep, csrc, cea, H1);
    // ---- layer 2: H1[30000,512] -> QKVS[30000,1024]
    gemm_bf16_k<<<dim3(1024 / 128, mblocks), 256, 0, stream>>>(H1, Wc2, bc2, QKVS, NN, 512, 1024);
    aggregate_k<4, 64, true><<<NN / 4, 256, 0, stream>>>(QKVS, 1024, e2w, basep, csrc, cea, H2);
    // ---- layer 3: H2[30000,256] -> QKVS[30000,512]
    gemm_bf16_k<<<dim3(512 / 128, mblocks), 256, 0, stream>>>(H2, Wc3, bc3, QKVS, NN, 256, 512);
    aggregate_k<1, 128, false><<<NN / 4, 256, 0, stream>>>(QKVS, 512, e3w, basep, csrc, cea, H3);

    // ---- fused pool + head
    pool_head_k<<<GG, 256, 0, stream>>>(H3, gstart, lw, lb, (float*)d_out);
}

// Round 7
// 775.028 us; speedup vs baseline: 3.1831x; 1.0244x over previous
//
#include <hip/hip_runtime.h>
#include <hip/hip_bf16.h>
#include <cstdint>

#define NN 30000
#define EE 480000
#define GG 64

typedef __attribute__((ext_vector_type(8))) short bf16x8;
typedef __attribute__((ext_vector_type(4))) float float4v;
typedef __attribute__((ext_vector_type(4))) unsigned short ushort4v;

static __device__ inline unsigned short f2bf(float f) {
    unsigned u = __float_as_uint(f);
    unsigned r = (u + 0x7fff + ((u >> 16) & 1)) >> 16;   // RNE
    return (unsigned short)r;
}
static __device__ inline float bf2f(unsigned short u) {
    return __uint_as_float(((unsigned)u) << 16);
}

// ---------------------------------------------------------------- CSR build
__global__ void count_deg_k(const int* __restrict__ ei, int* __restrict__ deg) {
    int e = blockIdx.x * 256 + threadIdx.x;
    if (e < EE) atomicAdd(&deg[ei[EE + e]], 1);
}

// 1 block, 1024 threads; each thread scans CH contiguous elems, one LDS tree.
__global__ __launch_bounds__(1024) void scan_excl_k(const int* __restrict__ deg,
                                                    int* __restrict__ basep) {
    constexpr int CH = (NN + 1024) / 1024 + 1;   // 30
    __shared__ int buf[1024];
    int t = threadIdx.x;
    int b0 = t * CH;
    int loc[CH];
    int s = 0;
#pragma unroll
    for (int i = 0; i < CH; i++) {
        int idx = b0 + i;
        int v = (idx < NN) ? deg[idx] : 0;
        loc[i] = s;
        s += v;
    }
    buf[t] = s;
    __syncthreads();
    for (int off = 1; off < 1024; off <<= 1) {
        int tv = (t >= off) ? buf[t - off] : 0;
        __syncthreads();
        buf[t] += tv;
        __syncthreads();
    }
    int base = (t > 0) ? buf[t - 1] : 0;
#pragma unroll
    for (int i = 0; i < CH; i++) {
        int idx = b0 + i;
        if (idx <= NN) basep[idx] = base + loc[i];
    }
}

__global__ void fill_csr_k(const int* __restrict__ ei, const float* __restrict__ ea,
                           const int* __restrict__ basep, int* __restrict__ cnt,
                           int* __restrict__ csrc, float* __restrict__ cea) {
    int e = blockIdx.x * 256 + threadIdx.x;
    if (e < EE) {
        int d = ei[EE + e];
        int pos = basep[d] + atomicAdd(&cnt[d], 1);
        csrc[pos] = ei[e];
        cea[pos] = ea[e];
    }
}

// batch is sorted: group start offsets
__global__ void gbound_k(const int* __restrict__ batch, int* __restrict__ gstart) {
    int i = blockIdx.x * 256 + threadIdx.x;
    if (i >= NN) return;
    int cur = batch[i];
    if (i == 0) {
        for (int g = 0; g <= cur; ++g) gstart[g] = 0;
    } else {
        int prev = batch[i - 1];
        for (int g = prev + 1; g <= cur; ++g) gstart[g] = i;
    }
    if (i == NN - 1) {
        for (int g = cur + 1; g <= GG; ++g) gstart[g] = NN;
    }
}

// ---------------------------------------------------------------- prep
struct PrepDesc { const float* src; void* dst; int rows; int cols; int blk0; int mode; };
#define NDESC 25
struct PrepArgs { PrepDesc d[NDESC]; };

__global__ __launch_bounds__(256) void prep_k(PrepArgs args) {
    int b = blockIdx.x;
    PrepDesc dd = args.d[0];
#pragma unroll
    for (int i = 1; i < NDESC; i++)
        if (b >= args.d[i].blk0) dd = args.d[i];
    int rel = b - dd.blk0;
    int total = dd.rows * dd.cols;
    int base = rel * 1024 + threadIdx.x;
    if (dd.mode == 0) {
        unsigned short* dst = (unsigned short*)dd.dst;
        for (int j = 0; j < 4; j++) {
            int i = base + j * 256;
            if (i < total) dst[i] = f2bf(dd.src[i]);
        }
    } else if (dd.mode == 1) {
        unsigned short* dst = (unsigned short*)dd.dst;
        for (int j = 0; j < 4; j++) {
            int i = base + j * 256;
            if (i < total) {
                int n = i / dd.rows, k = i - n * dd.rows;
                dst[i] = f2bf(dd.src[(size_t)k * dd.cols + n]);
            }
        }
    } else {
        float* dst = (float*)dd.dst;
        for (int j = 0; j < 4; j++) {
            int i = base + j * 256;
            if (i < total) dst[i] = dd.src[i];
        }
    }
}

// ---------------------------------------------------------------- bf16 MFMA GEMM
// C[M][N] = A[M][K] @ Wt[N][K]^T + bias.  128x128 tile, BK=32, dbuf LDS,
// bijective XCD swizzle (contiguous tile range per XCD -> A-panel L2 reuse).
__global__ __launch_bounds__(256) void gemm_bf16_k(
    const unsigned short* __restrict__ A, const unsigned short* __restrict__ Wt,
    const float* __restrict__ bias, unsigned short* __restrict__ C,
    int M, int K, int N) {
    __shared__ unsigned short As[2][4096];
    __shared__ unsigned short Bs[2][4096];
    int tid = threadIdx.x;
    int lane = tid & 63, wid = tid >> 6;
    int wm = wid >> 1, wn = wid & 1;

    // bijective XCD-aware remap of linear block id (m204)
    int gx = gridDim.x;
    int T = gx * gridDim.y;
    int lid = blockIdx.y * gx + blockIdx.x;
    int qq = T >> 3, rr = T & 7;
    int xcd = lid & 7, pos = lid >> 3;
    int tile = ((xcd < rr) ? xcd * (qq + 1) : rr * (qq + 1) + (xcd - rr) * qq) + pos;
    int by = tile / gx, bx = tile - by * gx;
    int row0 = by * 128, n0 = bx * 128;

    float4v acc[4][4];
#pragma unroll
    for (int i = 0; i < 4; i++)
#pragma unroll
        for (int j = 0; j < 4; j++) acc[i][j] = (float4v)0.f;

    auto stage = [&](int buf, int k0) {
#pragma unroll
        for (int i = 0; i < 2; ++i) {
            int chunkbase = i * 256 + wid * 64;          // wave-uniform
            int chunk = chunkbase + lane;
            int r = chunk & 127, kc = chunk >> 7;
            int rowA = row0 + r; if (rowA >= M) rowA = M - 1;
            const unsigned short* ga = A + (size_t)rowA * K + (k0 + kc * 8);
            __builtin_amdgcn_global_load_lds(
                (const __attribute__((address_space(1))) void*)ga,
                (__attribute__((address_space(3))) void*)(As[buf] + (size_t)chunkbase * 8),
                16, 0, 0);
            const unsigned short* gb = Wt + (size_t)(n0 + r) * K + (k0 + kc * 8);
            __builtin_amdgcn_global_load_lds(
                (const __attribute__((address_space(1))) void*)gb,
                (__attribute__((address_space(3))) void*)(Bs[buf] + (size_t)chunkbase * 8),
                16, 0, 0);
        }
    };

    stage(0, 0);
    asm volatile("s_waitcnt vmcnt(0)" ::: "memory");
    __syncthreads();

    int NT = K >> 5;
    for (int t = 0; t < NT; ++t) {
        int b = t & 1;
        if (t + 1 < NT) stage(b ^ 1, (t + 1) << 5);
        bf16x8 af[4], bfr[4];
#pragma unroll
        for (int mi = 0; mi < 4; mi++)
            af[mi] = *(const bf16x8*)(As[b] + ((lane >> 4) * 128 + wm * 64 + mi * 16 + (lane & 15)) * 8);
#pragma unroll
        for (int ni = 0; ni < 4; ni++)
            bfr[ni] = *(const bf16x8*)(Bs[b] + ((lane >> 4) * 128 + wn * 64 + ni * 16 + (lane & 15)) * 8);
#pragma unroll
        for (int mi = 0; mi < 4; mi++)
#pragma unroll
            for (int ni = 0; ni < 4; ni++)
                acc[mi][ni] = __builtin_amdgcn_mfma_f32_16x16x32_bf16(
                    bfr[ni], af[mi], acc[mi][ni], 0, 0, 0);
        asm volatile("s_waitcnt vmcnt(0)" ::: "memory");
        __syncthreads();
    }

    float4v bias4[4];
#pragma unroll
    for (int ni = 0; ni < 4; ni++)
        bias4[ni] = *(const float4v*)&bias[n0 + wn * 64 + ni * 16 + (lane >> 4) * 4];
#pragma unroll
    for (int mi = 0; mi < 4; mi++) {
        int row = row0 + wm * 64 + mi * 16 + (lane & 15);
        if (row < M) {
#pragma unroll
            for (int ni = 0; ni < 4; ni++) {
                int colb = n0 + wn * 64 + ni * 16 + (lane >> 4) * 4;
                ushort4v pk;
#pragma unroll
                for (int r = 0; r < 4; r++) pk[r] = f2bf(acc[mi][ni][r] + bias4[ni][r]);
                *(ushort4v*)(C + (size_t)row * N + colb) = pk;
            }
        }
    }
}

// ---------------------------------------------------------------- aggregate
template <int VEC> struct RawVec;
template <> struct RawVec<2> { using T = unsigned; };
template <> struct RawVec<4> { using T = uint2; };
template <> struct RawVec<8> { using T = uint4; };

static __device__ inline void unpackr(unsigned v, float (&r)[2]) {
    r[0] = __uint_as_float(v << 16); r[1] = __uint_as_float(v & 0xffff0000u);
}
static __device__ inline void unpackr(uint2 v, float (&r)[4]) {
    r[0] = __uint_as_float(v.x << 16); r[1] = __uint_as_float(v.x & 0xffff0000u);
    r[2] = __uint_as_float(v.y << 16); r[3] = __uint_as_float(v.y & 0xffff0000u);
}
static __device__ inline void unpackr(uint4 v, float (&r)[8]) {
    r[0] = __uint_as_float(v.x << 16); r[1] = __uint_as_float(v.x & 0xffff0000u);
    r[2] = __uint_as_float(v.y << 16); r[3] = __uint_as_float(v.y & 0xffff0000u);
    r[4] = __uint_as_float(v.z << 16); r[5] = __uint_as_float(v.z & 0xffff0000u);
    r[6] = __uint_as_float(v.w << 16); r[7] = __uint_as_float(v.w & 0xffff0000u);
}

template <int VEC>
__device__ inline void loadbf(const unsigned short* __restrict__ p, float (&r)[VEC]) {
    typename RawVec<VEC>::T v = *(const typename RawVec<VEC>::T*)p;
    unpackr(v, r);
}
template <int VEC>
__device__ inline void loadf32(const float* __restrict__ p, float (&r)[VEC]) {
    if constexpr (VEC == 2) {
        float2 t = *reinterpret_cast<const float2*>(p);
        r[0] = t.x; r[1] = t.y;
    } else {
#pragma unroll
        for (int i = 0; i < VEC; i += 4) {
            float4 t = *reinterpret_cast<const float4*>(p + i);
            r[i] = t.x; r[i + 1] = t.y; r[i + 2] = t.z; r[i + 3] = t.w;
        }
    }
}
template <int VEC>
__device__ inline void storebf(unsigned short* __restrict__ p, const float (&r)[VEC]) {
    unsigned w[VEC / 2];
#pragma unroll
    for (int i = 0; i < VEC / 2; i++)
        w[i] = (unsigned)f2bf(r[2 * i]) | ((unsigned)f2bf(r[2 * i + 1]) << 16);
    if constexpr (VEC == 2) *(unsigned*)p = w[0];
    else if constexpr (VEC == 4) *(uint2*)p = make_uint2(w[0], w[1]);
    else *(uint4*)p = make_uint4(w[0], w[1], w[2], w[3]);
}

// One wave per node. QKVS row: [Q | K | V | S], stride SR = 4F bf16.
// Wave-cooperative edge-index chunk load (64 edges / coalesced load) +
// 4-deep packed-register K/V prefetch via __shfl'd indices (no index-load
// dependency in the gather chain). Max-free softmax.
template <int H, int D, bool RELU>
__global__ __launch_bounds__(256) void aggregate_k(
    const unsigned short* __restrict__ QKVS, int SR,
    const float* __restrict__ ew,
    const int* __restrict__ rowptr, const int* __restrict__ csrc,
    const float* __restrict__ cea, unsigned short* __restrict__ Hout) {
    constexpr int F = H * D;
    constexpr int VEC = F / 64;
    constexpr int L = 64 / H;
    using RawT = typename RawVec<VEC>::T;
    int lane = threadIdx.x & 63;
    int node = blockIdx.x * 4 + (threadIdx.x >> 6);
    if (node >= NN) return;

    const unsigned short* qrow = QKVS + (size_t)node * SR;
    float q[VEC], ewv[VEC], acc[VEC];
    loadbf<VEC>(qrow + lane * VEC, q);
    loadf32<VEC>(ew + lane * VEC, ewv);
#pragma unroll
    for (int i = 0; i < VEC; i++) acc[i] = 0.f;

    float den = 0.f;
    const float isd = rsqrtf((float)D);
    int beg = rowptr[node], end = rowptr[node + 1];

    for (int cb = beg; cb < end; cb += 64) {
        int cnt = min(end - cb, 64);
        int gi = cb + lane;
        int sidx = (gi < end) ? csrc[gi] : 0;        // one coalesced load: 64 indices
        float sea = (gi < end) ? cea[gi] : 0.f;      // one coalesced load: 64 edge attrs

        RawT k0r, k1r, k2r, k3r, v0r, v1r, v2r, v3r;
        float e0 = 0.f, e1 = 0.f, e2 = 0.f, e3 = 0.f;
        auto fetch = [&](int t, RawT& kr, RawT& vr, float& ea) {
            int s = __shfl(sidx, t, 64);             // index from registers, no mem dep
            ea = __shfl(sea, t, 64);
            const unsigned short* b = QKVS + (size_t)s * SR + F + lane * VEC;
            kr = *(const RawT*)b;
            vr = *(const RawT*)(b + F);
        };
        auto process = [&](RawT kr, RawT vr, float ea) {
            float kv[VEC], vv[VEC], t[VEC];
            unpackr(kr, kv);
            unpackr(vr, vv);
            float p = 0.f;
#pragma unroll
            for (int i = 0; i < VEC; i++) { t[i] = ea * ewv[i]; p += q[i] * (kv[i] + t[i]); }
#pragma unroll
            for (int off = 1; off < L; off <<= 1) p += __shfl_xor(p, off, 64);
            float w = __expf(fminf(p * isd, 30.f));
            den += w;
#pragma unroll
            for (int i = 0; i < VEC; i++) acc[i] += w * (vv[i] + t[i]);
        };

        if (cnt > 0) fetch(0, k0r, v0r, e0);
        if (cnt > 1) fetch(1, k1r, v1r, e1);
        if (cnt > 2) fetch(2, k2r, v2r, e2);
        if (cnt > 3) fetch(3, k3r, v3r, e3);

        for (int t = 0; t < cnt; t += 4) {
            process(k0r, v0r, e0);
            if (t + 4 < cnt) fetch(t + 4, k0r, v0r, e0);
            if (t + 1 < cnt) {
                process(k1r, v1r, e1);
                if (t + 5 < cnt) fetch(t + 5, k1r, v1r, e1);
            }
            if (t + 2 < cnt) {
                process(k2r, v2r, e2);
                if (t + 6 < cnt) fetch(t + 6, k2r, v2r, e2);
            }
            if (t + 3 < cnt) {
                process(k3r, v3r, e3);
                if (t + 7 < cnt) fetch(t + 7, k3r, v3r, e3);
            }
        }
    }

    float rden = (den > 0.f) ? 1.f / den : 0.f;
    float sv[VEC];
    loadbf<VEC>(qrow + 3 * F + lane * VEC, sv);
    float o[VEC];
#pragma unroll
    for (int i = 0; i < VEC; i++) {
        float v = acc[i] * rden + sv[i];
        o[i] = RELU ? fmaxf(v, 0.f) : v;
    }
    storebf<VEC>(Hout + (size_t)node * F + lane * VEC, o);
}

// ---------------------------------------------------------------- pool+head (fused)
__global__ __launch_bounds__(256) void pool_head_k(
    const unsigned short* __restrict__ h3, const int* __restrict__ gstart,
    const float* __restrict__ lw, const float* __restrict__ lb,
    float* __restrict__ out) {
    __shared__ float part[256];
    __shared__ float pooled[128];
    int g = blockIdx.x;
    int beg = gstart[g], end = gstart[g + 1];
    int d = threadIdx.x & 127, half = threadIdx.x >> 7;
    float s = 0.f;
    for (int node = beg + half; node < end; node += 2)
        s += bf2f(h3[(size_t)node * 128 + d]);
    part[threadIdx.x] = s;
    __syncthreads();
    if (threadIdx.x < 128) {
        float cnt = fmaxf((float)(end - beg), 1.0f);
        pooled[threadIdx.x] = (part[threadIdx.x] + part[threadIdx.x + 128]) / cnt;
    }
    __syncthreads();
    if (threadIdx.x < 13) {
        float acc = lb[threadIdx.x];
        for (int dd = 0; dd < 128; ++dd)
            acc += pooled[dd] * lw[dd * 13 + threadIdx.x];
        out[g * 13 + threadIdx.x] = acc;
    }
}

__global__ void ws_fail_k(float* __restrict__ out, int n) {
    int i = blockIdx.x * 256 + threadIdx.x;
    if (i < n) out[i] = -12345.0f;
}

// ---------------------------------------------------------------- launch
extern "C" void kernel_launch(void* const* d_in, const int* in_sizes, int n_in,
                              void* d_out, int out_size, void* d_ws, size_t ws_size,
                              hipStream_t stream) {
    const float* x   = (const float*)d_in[0];
    const int*   ei  = (const int*)d_in[1];
    const float* ea  = (const float*)d_in[2];
    const int*   bat = (const int*)d_in[3];
    const float* W1[4] = {(const float*)d_in[4], (const float*)d_in[6], (const float*)d_in[8], (const float*)d_in[11]};
    const float* B1[4] = {(const float*)d_in[5], (const float*)d_in[7], (const float*)d_in[9], (const float*)d_in[12]};
    const float* e1w = (const float*)d_in[10];
    const float* W2[4] = {(const float*)d_in[13], (const float*)d_in[15], (const float*)d_in[17], (const float*)d_in[20]};
    const float* B2[4] = {(const float*)d_in[14], (const float*)d_in[16], (const float*)d_in[18], (const float*)d_in[21]};
    const float* e2w = (const float*)d_in[19];
    const float* W3[4] = {(const float*)d_in[22], (const float*)d_in[24], (const float*)d_in[26], (const float*)d_in[29]};
    const float* B3[4] = {(const float*)d_in[23], (const float*)d_in[25], (const float*)d_in[27], (const float*)d_in[30]};
    const float* e3w = (const float*)d_in[28];
    const float* lw  = (const float*)d_in[31];
    const float* lb  = (const float*)d_in[32];

    char* wsb = (char*)d_ws;
    size_t off = 0;
    auto alloc_b = [&](size_t bytes) {
        void* p = wsb + off;
        off += (bytes + 255) & ~(size_t)255;
        return p;
    };
    unsigned short* xb   = (unsigned short*)alloc_b((size_t)NN * 256 * 2);
    unsigned short* Wc1  = (unsigned short*)alloc_b((size_t)2048 * 256 * 2);
    float*          bc1  = (float*)alloc_b(2048 * 4);
    unsigned short* Wc2  = (unsigned short*)alloc_b((size_t)1024 * 512 * 2);
    float*          bc2  = (float*)alloc_b(1024 * 4);
    unsigned short* Wc3  = (unsigned short*)alloc_b((size_t)512 * 256 * 2);
    float*          bc3  = (float*)alloc_b(512 * 4);
    unsigned short* QKVS = (unsigned short*)alloc_b((size_t)NN * 2048 * 2);
    unsigned short* H1   = (unsigned short*)alloc_b((size_t)NN * 512 * 2);
    unsigned short* H2   = (unsigned short*)alloc_b((size_t)NN * 256 * 2);
    unsigned short* H3   = (unsigned short*)alloc_b((size_t)NN * 128 * 2);
    int*   basep  = (int*)alloc_b((NN + 1) * 4);
    int*   csrc   = (int*)alloc_b((size_t)EE * 4);
    float* cea    = (float*)alloc_b((size_t)EE * 4);
    int*   gstart = (int*)alloc_b((GG + 1) * 4);
    size_t zstart = off;
    int*   deg    = (int*)alloc_b(NN * 4);
    int*   cnt    = (int*)alloc_b(NN * 4);
    size_t zbytes = off - zstart;

    if (ws_size < off) {
        ws_fail_k<<<(out_size + 255) / 256, 256, 0, stream>>>((float*)d_out, out_size);
        return;
    }

    hipMemsetAsync(wsb + zstart, 0, zbytes, stream);

    PrepArgs pa;
    int blk = 0, di = 0;
    auto add = [&](const float* src, void* dst, int rows, int cols, int mode) {
        pa.d[di].src = src; pa.d[di].dst = dst;
        pa.d[di].rows = rows; pa.d[di].cols = cols;
        pa.d[di].mode = mode; pa.d[di].blk0 = blk;
        blk += (rows * cols + 1023) / 1024;
        di++;
    };
    add(x, xb, NN * 256, 1, 0);
    for (int s = 0; s < 4; s++) add(W1[s], Wc1 + (size_t)s * 512 * 256, 256, 512, 1);
    for (int s = 0; s < 4; s++) add(B1[s], bc1 + s * 512, 512, 1, 2);
    for (int s = 0; s < 4; s++) add(W2[s], Wc2 + (size_t)s * 256 * 512, 512, 256, 1);
    for (int s = 0; s < 4; s++) add(B2[s], bc2 + s * 256, 256, 1, 2);
    for (int s = 0; s < 4; s++) add(W3[s], Wc3 + (size_t)s * 128 * 256, 256, 128, 1);
    for (int s = 0; s < 4; s++) add(B3[s], bc3 + s * 128, 128, 1, 2);
    prep_k<<<blk, 256, 0, stream>>>(pa);

    int eblocks = (EE + 255) / 256;
    count_deg_k<<<eblocks, 256, 0, stream>>>(ei, deg);
    scan_excl_k<<<1, 1024, 0, stream>>>(deg, basep);
    fill_csr_k<<<eblocks, 256, 0, stream>>>(ei, ea, basep, cnt, csrc, cea);
    gbound_k<<<(NN + 255) / 256, 256, 0, stream>>>(bat, gstart);

    int mblocks = (NN + 127) / 128;
    // ---- layer 1: x[30000,256] -> QKVS[30000,2048]
    gemm_bf16_k<<<dim3(2048 / 128, mblocks), 256, 0, stream>>>(xb, Wc1, bc1, QKVS, NN, 256, 2048);
    aggregate_k<8, 64, true><<<NN / 4, 256, 0, stream>>>(QKVS, 2048, e1w, basep, csrc, cea, H1);
    // ---- layer 2: H1[30000,512] -> QKVS[30000,1024]
    gemm_bf16_k<<<dim3(1024 / 128, mblocks), 256, 0, stream>>>(H1, Wc2, bc2, QKVS, NN, 512, 1024);
    aggregate_k<4, 64, true><<<NN / 4, 256, 0, stream>>>(QKVS, 1024, e2w, basep, csrc, cea, H2);
    // ---- layer 3: H2[30000,256] -> QKVS[30000,512]
    gemm_bf16_k<<<dim3(512 / 128, mblocks), 256, 0, stream>>>(H2, Wc3, bc3, QKVS, NN, 256, 512);
    aggregate_k<1, 128, false><<<NN / 4, 256, 0, stream>>>(QKVS, 512, e3w, basep, csrc, cea, H3);

    // ---- fused pool + head
    pool_head_k<<<GG, 256, 0, stream>>>(H3, gstart, lw, lb, (float*)d_out);
}